// Round 1
// baseline (4475.732 us; speedup 1.0000x reference)
//
#include <hip/hip_runtime.h>
#include <math.h>

#define BATCH 16
#define SEQ   1024
#define HID   441
#define NH    9

__constant__ int c_bounds[NH + 1] = {0, 7, 21, 49, 105, 161, 217, 273, 357, 441};

// ---------------------------------------------------------------------------
// GEMM: C[M,N] = A[M,K] @ B[K,N] + bias[N]     (fp32, 64x64 tile, BK=16)
// ---------------------------------------------------------------------------
__global__ __launch_bounds__(256)
void gemm_bias_kernel(const float* __restrict__ A, const float* __restrict__ B,
                      const float* __restrict__ bias, float* __restrict__ C,
                      int M, int N, int K)
{
    const int BM = 64, BN = 64, BK = 16;
    __shared__ float As[BK][BM + 4];   // stride 68: conflict-free transpose store, 16B-aligned rows
    __shared__ float Bs[BK][BN];

    int tid = threadIdx.x;
    int bm = blockIdx.x * BM;
    int bn = blockIdx.y * BN;
    int tx = tid & 15, ty = tid >> 4;

    float acc[4][4] = {};

    for (int k0 = 0; k0 < K; k0 += BK) {
        // load A tile (64 rows x 16 cols), store transposed As[c][r]
#pragma unroll
        for (int i = 0; i < 4; ++i) {
            int idx = tid + i * 256;          // 0..1023
            int r = idx >> 4, c = idx & 15;
            int gc = k0 + c;
            As[c][r] = (gc < K) ? A[(size_t)(bm + r) * K + gc] : 0.f;
        }
        // load B tile (16 rows x 64 cols)
#pragma unroll
        for (int i = 0; i < 4; ++i) {
            int idx = tid + i * 256;
            int r = idx >> 6, c = idx & 63;
            int gr = k0 + r, gc = bn + c;
            Bs[r][c] = (gr < K && gc < N) ? B[(size_t)gr * N + gc] : 0.f;
        }
        __syncthreads();

#pragma unroll
        for (int kk = 0; kk < BK; ++kk) {
            float4 a4 = *reinterpret_cast<const float4*>(&As[kk][ty * 4]);
            float4 b4 = *reinterpret_cast<const float4*>(&Bs[kk][tx * 4]);
            float av[4] = {a4.x, a4.y, a4.z, a4.w};
            float bv[4] = {b4.x, b4.y, b4.z, b4.w};
#pragma unroll
            for (int i2 = 0; i2 < 4; ++i2)
#pragma unroll
                for (int j = 0; j < 4; ++j)
                    acc[i2][j] = fmaf(av[i2], bv[j], acc[i2][j]);
        }
        __syncthreads();
    }

#pragma unroll
    for (int i = 0; i < 4; ++i) {
        int gm = bm + ty * 4 + i;
#pragma unroll
        for (int j = 0; j < 4; ++j) {
            int gn = bn + tx * 4 + j;
            if (gn < N) C[(size_t)gm * N + gn] = acc[i][j] + bias[gn];
        }
    }
}

// ---------------------------------------------------------------------------
// Flash attention, fp32. One block = (batch b, head h, 64 query rows).
// K/V streamed in 64-key chunks through LDS with online softmax.
// ---------------------------------------------------------------------------
__global__ __launch_bounds__(256)
void attn_kernel(const float* __restrict__ q, const float* __restrict__ k,
                 const float* __restrict__ v, float* __restrict__ ctx)
{
    const int DS = 92;                 // LDS row stride (floats): 16B-aligned, 2-way banks
    __shared__ float Qs[64][DS];
    __shared__ float Ks[64][DS];
    __shared__ float Vs[64][DS];
    __shared__ float Ps[64][65];
    __shared__ float mrow[64], lrow[64], frow[64];

    int tid = threadIdx.x;
    int qt = blockIdx.x;               // 0..15  (query tile)
    int h  = blockIdx.y;               // 0..8   (head)
    int b  = blockIdx.z;               // 0..15  (batch)

    int s0 = c_bounds[h];
    int d  = c_bounds[h + 1] - s0;     // 7..84
    float scale = rsqrtf((float)d);
    int q0 = qt * 64;

    int lane = tid & 63, wid = tid >> 6;
    int tr = tid >> 4;                 // 0..15 : row group (4 rows)
    int tc = tid & 15;                 // 0..15 : col lane

    const float* qb = q + ((size_t)b * SEQ + q0) * HID + s0;
    const float* kb = k + ((size_t)b * SEQ) * HID + s0;
    const float* vb = v + ((size_t)b * SEQ) * HID + s0;

    // load Q tile (64 x d), coalesced: wave w loads rows w, w+4, ...
    for (int r = wid; r < 64; r += 4) {
        const float* src = qb + (size_t)r * HID;
        for (int c = lane; c < d; c += 64) Qs[r][c] = src[c];
    }
    if (tid < 64) { mrow[tid] = -1e30f; lrow[tid] = 0.f; }

    float o[4][6];                     // rows tr*4+i, cols tc+16*ci
#pragma unroll
    for (int i = 0; i < 4; ++i)
#pragma unroll
        for (int ci = 0; ci < 6; ++ci) o[i][ci] = 0.f;

    __syncthreads();

    int dv4 = d & ~3;

    for (int kt = 0; kt < SEQ; kt += 64) {
        // ---- load K/V chunk ----
        for (int r0 = wid; r0 < 64; r0 += 4) {
            const float* ksrc = kb + (size_t)(kt + r0) * HID;
            const float* vsrc = vb + (size_t)(kt + r0) * HID;
            for (int c = lane; c < d; c += 64) { Ks[r0][c] = ksrc[c]; Vs[r0][c] = vsrc[c]; }
        }
        __syncthreads();

        // ---- scores: rows tr*4+i, cols tc+16*jj ----
        float sc[4][4] = {};
        for (int x = 0; x < dv4; x += 4) {
            float4 qv[4];
#pragma unroll
            for (int i = 0; i < 4; ++i)
                qv[i] = *reinterpret_cast<const float4*>(&Qs[tr * 4 + i][x]);
#pragma unroll
            for (int jj = 0; jj < 4; ++jj) {
                float4 kv = *reinterpret_cast<const float4*>(&Ks[tc + 16 * jj][x]);
#pragma unroll
                for (int i = 0; i < 4; ++i) {
                    sc[i][jj] = fmaf(qv[i].x, kv.x, sc[i][jj]);
                    sc[i][jj] = fmaf(qv[i].y, kv.y, sc[i][jj]);
                    sc[i][jj] = fmaf(qv[i].z, kv.z, sc[i][jj]);
                    sc[i][jj] = fmaf(qv[i].w, kv.w, sc[i][jj]);
                }
            }
        }
        for (int x = dv4; x < d; ++x) {   // tail (d = 7, 14)
            float qv[4];
#pragma unroll
            for (int i = 0; i < 4; ++i) qv[i] = Qs[tr * 4 + i][x];
#pragma unroll
            for (int jj = 0; jj < 4; ++jj) {
                float kv = Ks[tc + 16 * jj][x];
#pragma unroll
                for (int i = 0; i < 4; ++i) sc[i][jj] = fmaf(qv[i], kv, sc[i][jj]);
            }
        }
#pragma unroll
        for (int i = 0; i < 4; ++i)
#pragma unroll
            for (int jj = 0; jj < 4; ++jj)
                Ps[tr * 4 + i][tc + 16 * jj] = sc[i][jj] * scale;
        __syncthreads();

        // ---- row max + rescale factor ----
        if (tid < 64) {
            float cm = -1e30f;
#pragma unroll 8
            for (int j = 0; j < 64; ++j) cm = fmaxf(cm, Ps[tid][j]);
            float nm = fmaxf(mrow[tid], cm);
            frow[tid] = __expf(mrow[tid] - nm);
            mrow[tid] = nm;
        }
        __syncthreads();

        // ---- exp in place ----
#pragma unroll
        for (int i = 0; i < 4; ++i) {
            float m = mrow[tr * 4 + i];
#pragma unroll
            for (int jj = 0; jj < 4; ++jj) {
                int col = tc + 16 * jj;
                Ps[tr * 4 + i][col] = __expf(Ps[tr * 4 + i][col] - m);
            }
        }
        __syncthreads();

        // ---- l update (wave 0 rows) ----
        if (tid < 64) {
            float ssum = 0.f;
#pragma unroll 8
            for (int j = 0; j < 64; ++j) ssum += Ps[tid][j];
            lrow[tid] = lrow[tid] * frow[tid] + ssum;
        }

        // ---- rescale o, accumulate PV ----
#pragma unroll
        for (int i = 0; i < 4; ++i) {
            float f = frow[tr * 4 + i];
#pragma unroll
            for (int ci = 0; ci < 6; ++ci) o[i][ci] *= f;
        }
        for (int j = 0; j < 64; ++j) {
            float p0 = Ps[tr * 4 + 0][j];
            float p1 = Ps[tr * 4 + 1][j];
            float p2 = Ps[tr * 4 + 2][j];
            float p3 = Ps[tr * 4 + 3][j];
#pragma unroll
            for (int ci = 0; ci < 6; ++ci) {
                int c = tc + 16 * ci;
                if (c < d) {
                    float vv = Vs[j][c];
                    o[0][ci] = fmaf(p0, vv, o[0][ci]);
                    o[1][ci] = fmaf(p1, vv, o[1][ci]);
                    o[2][ci] = fmaf(p2, vv, o[2][ci]);
                    o[3][ci] = fmaf(p3, vv, o[3][ci]);
                }
            }
        }
        __syncthreads();
    }

    // ---- write ctx ----
#pragma unroll
    for (int i = 0; i < 4; ++i) {
        int row = tr * 4 + i;
        float linv = 1.f / lrow[row];
        float* dst = ctx + ((size_t)b * SEQ + q0 + row) * HID + s0;
#pragma unroll
        for (int ci = 0; ci < 6; ++ci) {
            int c = tc + 16 * ci;
            if (c < d) dst[c] = o[i][ci] * linv;
        }
    }
}

// ---------------------------------------------------------------------------
extern "C" void kernel_launch(void* const* d_in, const int* in_sizes, int n_in,
                              void* d_out, int out_size, void* d_ws, size_t ws_size,
                              hipStream_t stream)
{
    const float* hs = (const float*)d_in[0];
    const float* Wq = (const float*)d_in[1];
    const float* bq = (const float*)d_in[2];
    const float* Wk = (const float*)d_in[3];
    const float* bk = (const float*)d_in[4];
    const float* Wv = (const float*)d_in[5];
    const float* bv = (const float*)d_in[6];
    const float* Wo = (const float*)d_in[7];
    const float* bo = (const float*)d_in[8];
    float* out = (float*)d_out;

    size_t elems = (size_t)BATCH * SEQ * HID;
    // q staged in d_out (overwritten by the final GEMM after it's consumed);
    // k, v, ctx in workspace (3 * 28.9 MB = 86.7 MB)
    float* qbuf = out;
    float* kbuf = (float*)d_ws;
    float* vbuf = kbuf + elems;
    float* cbuf = vbuf + elems;

    int M = BATCH * SEQ;
    dim3 gg(M / 64, (HID + 63) / 64);   // 256 x 7

    gemm_bias_kernel<<<gg, 256, 0, stream>>>(hs, Wq, bq, qbuf, M, HID, HID);
    gemm_bias_kernel<<<gg, 256, 0, stream>>>(hs, Wk, bk, kbuf, M, HID, HID);
    gemm_bias_kernel<<<gg, 256, 0, stream>>>(hs, Wv, bv, vbuf, M, HID, HID);

    dim3 ga(SEQ / 64, NH, BATCH);       // 16 x 9 x 16
    attn_kernel<<<ga, 256, 0, stream>>>(qbuf, kbuf, vbuf, cbuf);

    gemm_bias_kernel<<<gg, 256, 0, stream>>>(cbuf, Wo, bo, out, M, HID, HID);
}

// Round 2
// 2372.730 us; speedup vs baseline: 1.8863x; 1.8863x over previous
//
#include <hip/hip_runtime.h>
#include <math.h>

#define BATCH 16
#define SEQ   1024
#define HID   441
#define NH    9
#define PB    544                 // sum of padded head dims
#define PBE   (SEQ * PB)          // padded elems per batch

typedef __attribute__((ext_vector_type(8))) short bf16x8;
typedef __attribute__((ext_vector_type(4))) float f32x4;

__constant__ int c_bounds[NH + 1] = {0, 7, 21, 49, 105, 161, 217, 273, 357, 441};
__constant__ int c_dpad[NH] = {32, 32, 32, 64, 64, 64, 64, 96, 96};
__constant__ int c_cum[NH]  = {0, 32, 64, 96, 160, 224, 288, 352, 448};

__device__ __forceinline__ ushort f2bf(float x) {
    union { float f; unsigned u; } v; v.f = x;
    unsigned r = v.u + 0x7FFF + ((v.u >> 16) & 1);   // RNE
    return (ushort)(r >> 16);
}

// ---------------------------------------------------------------------------
// GEMM: C[M,N] = A[M,K] @ B[K,N] + bias
// MODE 0: fp32 row-major out. MODE 1: bf16 scatter into padded qkv layout.
// ---------------------------------------------------------------------------
template<int MODE>
__global__ __launch_bounds__(256)
void gemm_bias(const float* __restrict__ A, const float* __restrict__ B,
               const float* __restrict__ bias, void* __restrict__ Cout,
               int M, int N, int K)
{
    const int BM = 64, BN = 64, BK = 16;
    __shared__ float As[BK][BM + 4];
    __shared__ float Bs[BK][BN];

    int tid = threadIdx.x;
    int bm = blockIdx.x * BM;
    int bn = blockIdx.y * BN;
    int tx = tid & 15, ty = tid >> 4;

    float acc[4][4] = {};

    for (int k0 = 0; k0 < K; k0 += BK) {
#pragma unroll
        for (int i = 0; i < 4; ++i) {
            int idx = tid + i * 256;
            int r = idx >> 4, c = idx & 15;
            int gc = k0 + c;
            As[c][r] = (gc < K) ? A[(size_t)(bm + r) * K + gc] : 0.f;
        }
#pragma unroll
        for (int i = 0; i < 4; ++i) {
            int idx = tid + i * 256;
            int r = idx >> 6, c = idx & 63;
            int gr = k0 + r, gc = bn + c;
            Bs[r][c] = (gr < K && gc < N) ? B[(size_t)gr * N + gc] : 0.f;
        }
        __syncthreads();

#pragma unroll
        for (int kk = 0; kk < BK; ++kk) {
            float4 a4 = *reinterpret_cast<const float4*>(&As[kk][ty * 4]);
            float4 b4 = *reinterpret_cast<const float4*>(&Bs[kk][tx * 4]);
            float av[4] = {a4.x, a4.y, a4.z, a4.w};
            float bv[4] = {b4.x, b4.y, b4.z, b4.w};
#pragma unroll
            for (int i2 = 0; i2 < 4; ++i2)
#pragma unroll
                for (int j = 0; j < 4; ++j)
                    acc[i2][j] = fmaf(av[i2], bv[j], acc[i2][j]);
        }
        __syncthreads();
    }

#pragma unroll
    for (int i = 0; i < 4; ++i) {
        int gm = bm + ty * 4 + i;
#pragma unroll
        for (int j = 0; j < 4; ++j) {
            int gn = bn + tx * 4 + j;
            if (gn >= N) continue;
            float val = acc[i][j] + bias[gn];
            if (MODE == 0) {
                ((float*)Cout)[(size_t)gm * N + gn] = val;
            } else {
                int b = gm >> 10, s = gm & 1023;
                int h = 0;
                while (gn >= c_bounds[h + 1]) ++h;
                size_t dst = (size_t)b * PBE + ((size_t)c_cum[h] << 10)
                           + (size_t)s * c_dpad[h] + (gn - c_bounds[h]);
                ((ushort*)Cout)[dst] = f2bf(val);
            }
        }
    }
}

// ---------------------------------------------------------------------------
// MFMA flash attention. Block = (b, h, 64 q-rows); 4 waves x 16 rows each.
// 16x16x32 bf16 MFMA; Q/K frags direct from global (L2-resident);
// V transposed through LDS; P bounced through per-wave LDS.
// C-frag layout: col = lane&15, row = (lane>>4)*4 + reg  [verified m89/m91]
// A/B frag: row/col = lane&15, k = (lane>>4)*8 + j (contiguous 8 bf16)
// ---------------------------------------------------------------------------
__global__ __launch_bounds__(256)
void attn_mfma(const ushort* __restrict__ qp, const ushort* __restrict__ kp,
               const ushort* __restrict__ vp, float* __restrict__ ctx)
{
    __shared__ ushort Vt[96][72];        // V^T for current key tile: [dv][key]
    __shared__ ushort Ps[4][16][72];     // per-wave P tile: [qrow][key]

    int tid  = threadIdx.x;
    int wave = tid >> 6, lane = tid & 63;
    int lr = lane & 15, lg = lane >> 4;

    int h = blockIdx.y, b = blockIdx.z;
    int q0 = blockIdx.x * 64;
    int s0 = c_bounds[h];
    int d  = c_bounds[h + 1] - s0;
    int dp = c_dpad[h];                  // 32 / 64 / 96
    float scale = rsqrtf((float)d);

    size_t base = (size_t)b * PBE + ((size_t)c_cum[h] << 10);
    const ushort* Q  = qp + base;
    const ushort* Kb = kp + base;
    const ushort* Vb = vp + base;

    int ndt = dp >> 4;                   // output col tiles (2/4/6)
    int nxc = dp >> 5;                   // K-dim chunks for QK (1/2/3)

    // Q A-fragments, resident for the whole block
    bf16x8 aq[3];
    {
        int qrow = q0 + wave * 16 + lr;
        const ushort* qr = Q + (size_t)qrow * dp + lg * 8;
        for (int xc = 0; xc < nxc; ++xc)
            aq[xc] = *(const bf16x8*)(qr + xc * 32);
    }

    f32x4 o[6];
    for (int i = 0; i < 6; ++i) o[i] = (f32x4){0.f, 0.f, 0.f, 0.f};
    float mrow[4] = {-1e30f, -1e30f, -1e30f, -1e30f};
    float lrow[4] = {0.f, 0.f, 0.f, 0.f};

    for (int kt = 0; kt < SEQ; kt += 64) {
        // ---- stage V^T tile ----
        const ushort* Vsrc = Vb + (size_t)kt * dp;
        int total = 64 * dp;
        for (int idx = tid * 2; idx < total; idx += 512) {
            int key = idx / dp;
            int c   = idx - key * dp;
            ushort2 vv = *(const ushort2*)(Vsrc + idx);
            Vt[c][key]     = vv.x;
            Vt[c + 1][key] = vv.y;
        }
        __syncthreads();

        // ---- S = Q K^T (scores), 16x64 per wave ----
        f32x4 sc[4];
        for (int ct = 0; ct < 4; ++ct) {
            f32x4 s = {0.f, 0.f, 0.f, 0.f};
            const ushort* kr = Kb + (size_t)(kt + ct * 16 + lr) * dp + lg * 8;
            for (int xc = 0; xc < nxc; ++xc) {
                bf16x8 bk = *(const bf16x8*)(kr + xc * 32);
                s = __builtin_amdgcn_mfma_f32_16x16x32_bf16(aq[xc], bk, s, 0, 0, 0);
            }
            sc[ct] = s * scale;
        }

        // ---- online softmax (wave-parallel, 16-lane col groups) ----
        float mnew[4], fr[4];
#pragma unroll
        for (int r = 0; r < 4; ++r) {
            float mx = fmaxf(fmaxf(sc[0][r], sc[1][r]), fmaxf(sc[2][r], sc[3][r]));
#pragma unroll
            for (int off = 1; off < 16; off <<= 1)
                mx = fmaxf(mx, __shfl_xor(mx, off));
            mnew[r] = fmaxf(mrow[r], mx);
            fr[r] = __expf(mrow[r] - mnew[r]);
            mrow[r] = mnew[r];
        }
#pragma unroll
        for (int r = 0; r < 4; ++r) {
            float sum = 0.f;
#pragma unroll
            for (int ct = 0; ct < 4; ++ct) {
                float p = __expf(sc[ct][r] - mnew[r]);
                sum += p;
                Ps[wave][lg * 4 + r][lr + ct * 16] = f2bf(p);
            }
#pragma unroll
            for (int off = 1; off < 16; off <<= 1)
                sum += __shfl_xor(sum, off);
            lrow[r] = lrow[r] * fr[r] + sum;
        }

        // ---- rescale O, then O += P V ----
        for (int dt = 0; dt < ndt; ++dt)
#pragma unroll
            for (int r = 0; r < 4; ++r) o[dt][r] *= fr[r];

        bf16x8 ap0 = *(const bf16x8*)&Ps[wave][lr][lg * 8];        // keys 0..31
        bf16x8 ap1 = *(const bf16x8*)&Ps[wave][lr][32 + lg * 8];   // keys 32..63
        for (int dt = 0; dt < ndt; ++dt) {
            bf16x8 bv0 = *(const bf16x8*)&Vt[lr + 16 * dt][lg * 8];
            bf16x8 bv1 = *(const bf16x8*)&Vt[lr + 16 * dt][32 + lg * 8];
            o[dt] = __builtin_amdgcn_mfma_f32_16x16x32_bf16(ap0, bv0, o[dt], 0, 0, 0);
            o[dt] = __builtin_amdgcn_mfma_f32_16x16x32_bf16(ap1, bv1, o[dt], 0, 0, 0);
        }
        __syncthreads();   // Vt reuse next tile
    }

    // ---- write ctx (fp32, unpadded layout) ----
#pragma unroll
    for (int r = 0; r < 4; ++r) {
        float inv = 1.0f / lrow[r];
        int q = q0 + wave * 16 + lg * 4 + r;
        float* dst = ctx + ((size_t)b * SEQ + q) * HID + s0;
        for (int dt = 0; dt < ndt; ++dt) {
            int dv = lr + 16 * dt;
            if (dv < d) dst[dv] = o[dt][r] * inv;
        }
    }
}

// ---------------------------------------------------------------------------
extern "C" void kernel_launch(void* const* d_in, const int* in_sizes, int n_in,
                              void* d_out, int out_size, void* d_ws, size_t ws_size,
                              hipStream_t stream)
{
    const float* hs = (const float*)d_in[0];
    const float* Wq = (const float*)d_in[1];
    const float* bq = (const float*)d_in[2];
    const float* Wk = (const float*)d_in[3];
    const float* bk = (const float*)d_in[4];
    const float* Wv = (const float*)d_in[5];
    const float* bv = (const float*)d_in[6];
    const float* Wo = (const float*)d_in[7];
    const float* bo = (const float*)d_in[8];
    float* out = (float*)d_out;

    size_t pelem = (size_t)BATCH * PBE;            // 8,912,896 per tensor
    ushort* qp = (ushort*)d_ws;
    ushort* kp = qp + pelem;
    ushort* vp = kp + pelem;
    float* cbuf = (float*)(vp + pelem);            // fp32 ctx, 28.9 MB

    // zero qkv buffers so inter-head pad columns are exactly 0.0bf16
    hipMemsetAsync(d_ws, 0, 3 * pelem * sizeof(ushort), stream);

    int M = BATCH * SEQ;
    dim3 gg(M / 64, (HID + 63) / 64);              // 256 x 7

    gemm_bias<1><<<gg, 256, 0, stream>>>(hs, Wq, bq, qp, M, HID, HID);
    gemm_bias<1><<<gg, 256, 0, stream>>>(hs, Wk, bk, kp, M, HID, HID);
    gemm_bias<1><<<gg, 256, 0, stream>>>(hs, Wv, bv, vp, M, HID, HID);

    dim3 ga(SEQ / 64, NH, BATCH);                  // 16 x 9 x 16
    attn_mfma<<<ga, 256, 0, stream>>>(qp, kp, vp, cbuf);

    gemm_bias<0><<<gg, 256, 0, stream>>>(cbuf, Wo, bo, out, M, HID, HID);
}

// Round 3
// 2271.246 us; speedup vs baseline: 1.9706x; 1.0447x over previous
//
#include <hip/hip_runtime.h>
#include <math.h>

#define BATCH 16
#define SEQ   1024
#define HID   441
#define NH    9
#define PB    544                 // sum of padded head dims
#define PBE   (SEQ * PB)          // padded elems per batch

typedef __attribute__((ext_vector_type(8))) short bf16x8;
typedef __attribute__((ext_vector_type(4))) float f32x4;

__constant__ int c_bounds[NH + 1] = {0, 7, 21, 49, 105, 161, 217, 273, 357, 441};
__constant__ int c_dpad[NH] = {32, 32, 32, 64, 64, 64, 64, 96, 96};
__constant__ int c_cum[NH]  = {0, 32, 64, 96, 160, 224, 288, 352, 448};

__device__ __forceinline__ ushort f2bf(float x) {
    union { float f; unsigned u; } v; v.f = x;
    unsigned r = v.u + 0x7FFF + ((v.u >> 16) & 1);   // RNE
    return (ushort)(r >> 16);
}

// ---------------------------------------------------------------------------
// GEMM: C[M,N] = A[M,K] @ B[K,N] + bias
// MODE 0: fp32 row-major.
// MODE 1: bf16 scatter into padded row-major qkv layout [b][h][s][dpad].
// MODE 2: bf16 TRANSPOSED scatter [b][h][dv][s]  (for V)
// ---------------------------------------------------------------------------
template<int MODE>
__global__ __launch_bounds__(256)
void gemm_bias(const float* __restrict__ A, const float* __restrict__ B,
               const float* __restrict__ bias, void* __restrict__ Cout,
               int M, int N, int K)
{
    const int BM = 64, BN = 64, BK = 16;
    __shared__ float smem[BK * 68 + BK * 64];        // As | Bs ; reused as Ts in MODE 2
    float (*As)[68] = (float(*)[68])smem;
    float (*Bs)[64] = (float(*)[64])(smem + BK * 68);

    int tid = threadIdx.x;
    int bm = blockIdx.x * BM;
    int bn = blockIdx.y * BN;
    int tx = tid & 15, ty = tid >> 4;

    float acc[4][4] = {};

    for (int k0 = 0; k0 < K; k0 += BK) {
#pragma unroll
        for (int i = 0; i < 4; ++i) {
            int idx = tid + i * 256;
            int r = idx >> 4, c = idx & 15;
            int gc = k0 + c;
            As[c][r] = (gc < K) ? A[(size_t)(bm + r) * K + gc] : 0.f;
        }
#pragma unroll
        for (int i = 0; i < 4; ++i) {
            int idx = tid + i * 256;
            int r = idx >> 6, c = idx & 63;
            int gr = k0 + r, gc = bn + c;
            Bs[r][c] = (gr < K && gc < N) ? B[(size_t)gr * N + gc] : 0.f;
        }
        __syncthreads();

#pragma unroll
        for (int kk = 0; kk < BK; ++kk) {
            float4 a4 = *reinterpret_cast<const float4*>(&As[kk][ty * 4]);
            float4 b4 = *reinterpret_cast<const float4*>(&Bs[kk][tx * 4]);
            float av[4] = {a4.x, a4.y, a4.z, a4.w};
            float bv[4] = {b4.x, b4.y, b4.z, b4.w};
#pragma unroll
            for (int i2 = 0; i2 < 4; ++i2)
#pragma unroll
                for (int j = 0; j < 4; ++j)
                    acc[i2][j] = fmaf(av[i2], bv[j], acc[i2][j]);
        }
        __syncthreads();
    }

    if (MODE == 2) {
        // bf16 tile -> LDS, then transposed coalesced store [dv][s]
        ushort (*Ts)[66] = (ushort(*)[66])smem;      // 64 x 66 ushorts = 8448 B, fits
#pragma unroll
        for (int i = 0; i < 4; ++i)
#pragma unroll
            for (int j = 0; j < 4; ++j) {
                int gn = bn + tx * 4 + j;
                float val = acc[i][j] + ((gn < N) ? bias[gn] : 0.f);
                Ts[ty * 4 + i][tx * 4 + j] = f2bf(val);
            }
        __syncthreads();

        int dvl = tid >> 2;                          // 0..63 local col (dv)
        int chunk = tid & 3;                         // 0..3 : 16 s-values each
        int gn = bn + dvl;
        if (gn < N) {
            int h = 0;
            while (gn >= c_bounds[h + 1]) ++h;
            int b = bm >> 10, s0 = bm & 1023;
            size_t dst = (size_t)b * PBE
                       + ((size_t)(c_cum[h] + (gn - c_bounds[h])) << 10)
                       + s0 + chunk * 16;
            union { ushort u[8]; bf16x8 v; } pk;
#pragma unroll
            for (int half = 0; half < 2; ++half) {
#pragma unroll
                for (int j = 0; j < 8; ++j)
                    pk.u[j] = Ts[chunk * 16 + half * 8 + j][dvl];
                *(bf16x8*)((ushort*)Cout + dst + half * 8) = pk.v;
            }
        }
        return;
    }

#pragma unroll
    for (int i = 0; i < 4; ++i) {
        int gm = bm + ty * 4 + i;
#pragma unroll
        for (int j = 0; j < 4; ++j) {
            int gn = bn + tx * 4 + j;
            if (gn >= N) continue;
            float val = acc[i][j] + bias[gn];
            if (MODE == 0) {
                ((float*)Cout)[(size_t)gm * N + gn] = val;
            } else {
                int b = gm >> 10, s = gm & 1023;
                int h = 0;
                while (gn >= c_bounds[h + 1]) ++h;
                size_t dst = (size_t)b * PBE + ((size_t)c_cum[h] << 10)
                           + (size_t)s * c_dpad[h] + (gn - c_bounds[h]);
                ((ushort*)Cout)[dst] = f2bf(val);
            }
        }
    }
}

// ---------------------------------------------------------------------------
// MFMA flash attention, barrier-free.
// Block = (b, h, 64 q-rows); 4 independent waves x 16 q-rows.
// Q[s][dp], K[s][dp] row-major padded; V stored TRANSPOSED [dv][s].
// Q/K/V fragments direct from global (L2-resident); P through per-wave
// XOR-swizzled LDS (no __syncthreads anywhere).
// Softmax in exp2 domain (scale premultiplied by log2 e).
// ---------------------------------------------------------------------------
__global__ __launch_bounds__(256)
void attn_mfma(const ushort* __restrict__ qp, const ushort* __restrict__ kp,
               const ushort* __restrict__ vp, float* __restrict__ ctx)
{
    __shared__ ushort Ps[4][16][64];     // per-wave P tile, XOR-swizzled cols

    int tid  = threadIdx.x;
    int wave = tid >> 6, lane = tid & 63;
    int lr = lane & 15, lg = lane >> 4;

    int h = blockIdx.y, b = blockIdx.z;
    int q0 = blockIdx.x * 64;
    int s0 = c_bounds[h];
    int d  = c_bounds[h + 1] - s0;
    int dp = c_dpad[h];                  // 32 / 64 / 96
    float scale2 = rsqrtf((float)d) * 1.44269504089f;   // -> exp2 domain

    size_t base = (size_t)b * PBE + ((size_t)c_cum[h] << 10);
    const ushort* Q   = qp + base;       // [s][dp]
    const ushort* Kb  = kp + base;       // [s][dp]
    const ushort* Vtb = vp + base;       // [dv][1024]

    int ndt = dp >> 4;                   // output col tiles (2/4/6)
    int nxc = dp >> 5;                   // K-dim chunks for QK (1/2/3)
    int swz = (lr & 7) << 3;             // read-side XOR (row = lr)

    // Q A-fragments, resident for the whole block
    bf16x8 aq[3];
    {
        int qrow = q0 + wave * 16 + lr;
        const ushort* qr = Q + (size_t)qrow * dp + lg * 8;
        for (int xc = 0; xc < nxc; ++xc)
            aq[xc] = *(const bf16x8*)(qr + xc * 32);
    }

    f32x4 o[6];
    for (int i = 0; i < 6; ++i) o[i] = (f32x4){0.f, 0.f, 0.f, 0.f};
    float mrow[4] = {-1e30f, -1e30f, -1e30f, -1e30f};
    float lrow[4] = {0.f, 0.f, 0.f, 0.f};

    for (int kt = 0; kt < SEQ; kt += 64) {
        // ---- S = Q K^T (16 q x 64 keys per wave), exp2-scaled ----
        f32x4 sc[4];
        for (int ct = 0; ct < 4; ++ct) {
            f32x4 s = {0.f, 0.f, 0.f, 0.f};
            const ushort* kr = Kb + (size_t)(kt + ct * 16 + lr) * dp + lg * 8;
            for (int xc = 0; xc < nxc; ++xc) {
                bf16x8 bk = *(const bf16x8*)(kr + xc * 32);
                s = __builtin_amdgcn_mfma_f32_16x16x32_bf16(aq[xc], bk, s, 0, 0, 0);
            }
            sc[ct] = s * scale2;
        }

        // ---- online softmax (16-lane butterfly over key cols) ----
        float mnew[4], fr[4];
#pragma unroll
        for (int r = 0; r < 4; ++r) {
            float mx = fmaxf(fmaxf(sc[0][r], sc[1][r]), fmaxf(sc[2][r], sc[3][r]));
#pragma unroll
            for (int off = 1; off < 16; off <<= 1)
                mx = fmaxf(mx, __shfl_xor(mx, off));
            mnew[r] = fmaxf(mrow[r], mx);
            fr[r] = exp2f(mrow[r] - mnew[r]);
            mrow[r] = mnew[r];
        }
#pragma unroll
        for (int r = 0; r < 4; ++r) {
            int row = lg * 4 + r;
            int wsz = (row & 7) << 3;    // write-side XOR
            float sum = 0.f;
#pragma unroll
            for (int ct = 0; ct < 4; ++ct) {
                float p = exp2f(sc[ct][r] - mnew[r]);
                sum += p;
                Ps[wave][row][(lr + ct * 16) ^ wsz] = f2bf(p);
            }
#pragma unroll
            for (int off = 1; off < 16; off <<= 1)
                sum += __shfl_xor(sum, off);
            lrow[r] = lrow[r] * fr[r] + sum;
        }

        // ---- O = fr*O + P V ----
        bf16x8 ap0 = *(const bf16x8*)&Ps[wave][lr][(lg * 8) ^ swz];
        bf16x8 ap1 = *(const bf16x8*)&Ps[wave][lr][(32 + lg * 8) ^ swz];

        for (int dt = 0; dt < ndt; ++dt) {
            const ushort* vr = Vtb + ((size_t)(dt * 16 + lr) << 10) + kt + lg * 8;
            bf16x8 bv0 = *(const bf16x8*)vr;
            bf16x8 bv1 = *(const bf16x8*)(vr + 32);
#pragma unroll
            for (int r = 0; r < 4; ++r) o[dt][r] *= fr[r];
            o[dt] = __builtin_amdgcn_mfma_f32_16x16x32_bf16(ap0, bv0, o[dt], 0, 0, 0);
            o[dt] = __builtin_amdgcn_mfma_f32_16x16x32_bf16(ap1, bv1, o[dt], 0, 0, 0);
        }
    }

    // ---- write ctx (fp32, unpadded layout) ----
#pragma unroll
    for (int r = 0; r < 4; ++r) {
        float inv = 1.0f / lrow[r];
        int q = q0 + wave * 16 + lg * 4 + r;
        float* dst = ctx + ((size_t)b * SEQ + q) * HID + s0;
        for (int dt = 0; dt < ndt; ++dt) {
            int dv = lr + 16 * dt;
            if (dv < d) dst[dv] = o[dt][r] * inv;
        }
    }
}

// ---------------------------------------------------------------------------
extern "C" void kernel_launch(void* const* d_in, const int* in_sizes, int n_in,
                              void* d_out, int out_size, void* d_ws, size_t ws_size,
                              hipStream_t stream)
{
    const float* hs = (const float*)d_in[0];
    const float* Wq = (const float*)d_in[1];
    const float* bq = (const float*)d_in[2];
    const float* Wk = (const float*)d_in[3];
    const float* bk = (const float*)d_in[4];
    const float* Wv = (const float*)d_in[5];
    const float* bv = (const float*)d_in[6];
    const float* Wo = (const float*)d_in[7];
    const float* bo = (const float*)d_in[8];
    float* out = (float*)d_out;

    size_t pelem = (size_t)BATCH * PBE;            // 8,912,896 per tensor
    ushort* qp = (ushort*)d_ws;
    ushort* kp = qp + pelem;
    ushort* vp = kp + pelem;
    float* cbuf = (float*)(vp + pelem);            // fp32 ctx, 28.9 MB

    // zero qkv buffers so pad columns / pad dv-rows are exactly 0.0bf16
    hipMemsetAsync(d_ws, 0, 3 * pelem * sizeof(ushort), stream);

    int M = BATCH * SEQ;
    dim3 gg(M / 64, (HID + 63) / 64);              // 256 x 7

    gemm_bias<1><<<gg, 256, 0, stream>>>(hs, Wq, bq, qp, M, HID, HID);
    gemm_bias<1><<<gg, 256, 0, stream>>>(hs, Wk, bk, kp, M, HID, HID);
    gemm_bias<2><<<gg, 256, 0, stream>>>(hs, Wv, bv, vp, M, HID, HID);

    dim3 ga(SEQ / 64, NH, BATCH);                  // 16 x 9 x 16
    attn_mfma<<<ga, 256, 0, stream>>>(qp, kp, vp, cbuf);

    gemm_bias<0><<<gg, 256, 0, stream>>>(cbuf, Wo, bo, out, M, HID, HID);
}

// Round 4
// 891.456 us; speedup vs baseline: 5.0207x; 2.5478x over previous
//
#include <hip/hip_runtime.h>
#include <math.h>

#define BATCH 16
#define SEQ   1024
#define HID   441
#define NH    9
#define PB    544                 // sum of padded head dims
#define PBE   (SEQ * PB)          // padded elems per batch

typedef __attribute__((ext_vector_type(8))) short bf16x8;
typedef __attribute__((ext_vector_type(4))) float f32x4;

__constant__ int c_bounds[NH + 1] = {0, 7, 21, 49, 105, 161, 217, 273, 357, 441};
__constant__ int c_dpad[NH] = {32, 32, 32, 64, 64, 64, 64, 96, 96};
__constant__ int c_cum[NH]  = {0, 32, 64, 96, 160, 224, 288, 352, 448};

__device__ __forceinline__ ushort f2bf(float x) {
    union { float f; unsigned u; } v; v.f = x;
    unsigned r = v.u + 0x7FFF + ((v.u >> 16) & 1);   // RNE
    return (ushort)(r >> 16);
}

// ---------------------------------------------------------------------------
// GEMM: C[M,N] = A[M,K] @ B[K,N] + bias
// MODE 0: fp32 row-major.
// MODE 1: bf16 scatter into padded row-major qkv layout [b][h][s][dpad].
// MODE 2: bf16 TRANSPOSED scatter [b][h][dv][s]  (for V)
// ---------------------------------------------------------------------------
template<int MODE>
__global__ __launch_bounds__(256)
void gemm_bias(const float* __restrict__ A, const float* __restrict__ B,
               const float* __restrict__ bias, void* __restrict__ Cout,
               int M, int N, int K)
{
    const int BM = 64, BN = 64, BK = 16;
    __shared__ float smem[BK * 68 + BK * 64];        // As | Bs ; reused as Ts in MODE 2
    float (*As)[68] = (float(*)[68])smem;
    float (*Bs)[64] = (float(*)[64])(smem + BK * 68);

    int tid = threadIdx.x;
    int bm = blockIdx.x * BM;
    int bn = blockIdx.y * BN;
    int tx = tid & 15, ty = tid >> 4;

    float acc[4][4] = {};

    for (int k0 = 0; k0 < K; k0 += BK) {
#pragma unroll
        for (int i = 0; i < 4; ++i) {
            int idx = tid + i * 256;
            int r = idx >> 4, c = idx & 15;
            int gc = k0 + c;
            As[c][r] = (gc < K) ? A[(size_t)(bm + r) * K + gc] : 0.f;
        }
#pragma unroll
        for (int i = 0; i < 4; ++i) {
            int idx = tid + i * 256;
            int r = idx >> 6, c = idx & 63;
            int gr = k0 + r, gc = bn + c;
            Bs[r][c] = (gr < K && gc < N) ? B[(size_t)gr * N + gc] : 0.f;
        }
        __syncthreads();

#pragma unroll
        for (int kk = 0; kk < BK; ++kk) {
            float4 a4 = *reinterpret_cast<const float4*>(&As[kk][ty * 4]);
            float4 b4 = *reinterpret_cast<const float4*>(&Bs[kk][tx * 4]);
            float av[4] = {a4.x, a4.y, a4.z, a4.w};
            float bv[4] = {b4.x, b4.y, b4.z, b4.w};
#pragma unroll
            for (int i2 = 0; i2 < 4; ++i2)
#pragma unroll
                for (int j = 0; j < 4; ++j)
                    acc[i2][j] = fmaf(av[i2], bv[j], acc[i2][j]);
        }
        __syncthreads();
    }

    if (MODE == 2) {
        // bf16 tile -> LDS, then transposed coalesced store [dv][s]
        ushort (*Ts)[66] = (ushort(*)[66])smem;      // 64 x 66 ushorts
#pragma unroll
        for (int i = 0; i < 4; ++i)
#pragma unroll
            for (int j = 0; j < 4; ++j) {
                int gn = bn + tx * 4 + j;
                float val = acc[i][j] + ((gn < N) ? bias[gn] : 0.f);
                Ts[ty * 4 + i][tx * 4 + j] = f2bf(val);
            }
        __syncthreads();

        int dvl = tid >> 2;                          // 0..63 local col (dv)
        int chunk = tid & 3;                         // 0..3 : 16 s-values each
        int gn = bn + dvl;
        if (gn < N) {
            int h = 0;
            while (gn >= c_bounds[h + 1]) ++h;
            int b = bm >> 10, s0 = bm & 1023;
            size_t dst = (size_t)b * PBE
                       + ((size_t)(c_cum[h] + (gn - c_bounds[h])) << 10)
                       + s0 + chunk * 16;
            union { ushort u[8]; bf16x8 v; } pk;
#pragma unroll
            for (int half = 0; half < 2; ++half) {
#pragma unroll
                for (int j = 0; j < 8; ++j)
                    pk.u[j] = Ts[chunk * 16 + half * 8 + j][dvl];
                *(bf16x8*)((ushort*)Cout + dst + half * 8) = pk.v;
            }
        }
        return;
    }

#pragma unroll
    for (int i = 0; i < 4; ++i) {
        int gm = bm + ty * 4 + i;
#pragma unroll
        for (int j = 0; j < 4; ++j) {
            int gn = bn + tx * 4 + j;
            if (gn >= N) continue;
            float val = acc[i][j] + bias[gn];
            if (MODE == 0) {
                ((float*)Cout)[(size_t)gm * N + gn] = val;
            } else {
                int b = gm >> 10, s = gm & 1023;
                int h = 0;
                while (gn >= c_bounds[h + 1]) ++h;
                size_t dst = (size_t)b * PBE + ((size_t)c_cum[h] << 10)
                           + (size_t)s * c_dpad[h] + (gn - c_bounds[h]);
                ((ushort*)Cout)[dst] = f2bf(val);
            }
        }
    }
}

// ---------------------------------------------------------------------------
// MFMA flash attention body, DP = compile-time padded head dim (32/64/96).
// All loops constexpr-bounded -> fully unrolled -> arrays in registers
// (rule #20: runtime-indexed ext_vector arrays go to scratch).
// Block = (b, h, 64 q-rows); 4 independent waves x 16 q-rows, barrier-free.
// Q[s][dp], K[s][dp] row-major padded; V stored TRANSPOSED [dv][s].
// P bounced through per-wave XOR-swizzled LDS.
// ---------------------------------------------------------------------------
template<int DP>
__device__ __forceinline__
void attn_body(const ushort* __restrict__ qp, const ushort* __restrict__ kp,
               const ushort* __restrict__ vp, float* __restrict__ ctx,
               ushort (* __restrict__ Ps)[64], int h, int b, int q0)
{
    constexpr int NDT = DP / 16;         // output col tiles (2/4/6)
    constexpr int NXC = DP / 32;         // K-dim chunks for QK (1/2/3)

    int lane = threadIdx.x & 63;
    int wave = threadIdx.x >> 6;
    int lr = lane & 15, lg = lane >> 4;

    int s0 = c_bounds[h];
    int d  = c_bounds[h + 1] - s0;
    float scale2 = rsqrtf((float)d) * 1.44269504089f;   // exp2 domain

    size_t base = (size_t)b * PBE + ((size_t)c_cum[h] << 10);
    const ushort* Q   = qp + base;       // [s][DP]
    const ushort* Kb  = kp + base;       // [s][DP]
    const ushort* Vtb = vp + base;       // [dv][1024]

    int swz = (lr & 7) << 3;             // read-side XOR (row = lr)

    // Q A-fragments, resident for the whole block
    bf16x8 aq[NXC];
    {
        int qrow = q0 + wave * 16 + lr;
        const ushort* qr = Q + (size_t)qrow * DP + lg * 8;
#pragma unroll
        for (int xc = 0; xc < NXC; ++xc)
            aq[xc] = *(const bf16x8*)(qr + xc * 32);
    }

    f32x4 o[NDT];
#pragma unroll
    for (int i = 0; i < NDT; ++i) o[i] = (f32x4){0.f, 0.f, 0.f, 0.f};
    float mrow[4] = {-1e30f, -1e30f, -1e30f, -1e30f};
    float lrow[4] = {0.f, 0.f, 0.f, 0.f};

    for (int kt = 0; kt < SEQ; kt += 64) {
        // ---- S = Q K^T (16 q x 64 keys per wave), exp2-scaled ----
        f32x4 sc[4];
#pragma unroll
        for (int ct = 0; ct < 4; ++ct) {
            f32x4 s = {0.f, 0.f, 0.f, 0.f};
            const ushort* kr = Kb + (size_t)(kt + ct * 16 + lr) * DP + lg * 8;
#pragma unroll
            for (int xc = 0; xc < NXC; ++xc) {
                bf16x8 bk = *(const bf16x8*)(kr + xc * 32);
                s = __builtin_amdgcn_mfma_f32_16x16x32_bf16(aq[xc], bk, s, 0, 0, 0);
            }
            sc[ct] = s * scale2;
        }

        // ---- online softmax (16-lane butterfly over key cols) ----
        float mnew[4], fr[4];
#pragma unroll
        for (int r = 0; r < 4; ++r) {
            float mx = fmaxf(fmaxf(sc[0][r], sc[1][r]), fmaxf(sc[2][r], sc[3][r]));
#pragma unroll
            for (int off = 1; off < 16; off <<= 1)
                mx = fmaxf(mx, __shfl_xor(mx, off));
            mnew[r] = fmaxf(mrow[r], mx);
            fr[r] = exp2f(mrow[r] - mnew[r]);
            mrow[r] = mnew[r];
        }
#pragma unroll
        for (int r = 0; r < 4; ++r) {
            int row = lg * 4 + r;
            int wsz = (row & 7) << 3;    // write-side XOR
            float sum = 0.f;
#pragma unroll
            for (int ct = 0; ct < 4; ++ct) {
                float p = exp2f(sc[ct][r] - mnew[r]);
                sum += p;
                Ps[row][(lr + ct * 16) ^ wsz] = f2bf(p);
            }
#pragma unroll
            for (int off = 1; off < 16; off <<= 1)
                sum += __shfl_xor(sum, off);
            lrow[r] = lrow[r] * fr[r] + sum;
        }

        // ---- O = fr*O + P V ----
        bf16x8 ap0 = *(const bf16x8*)&Ps[lr][(lg * 8) ^ swz];
        bf16x8 ap1 = *(const bf16x8*)&Ps[lr][(32 + lg * 8) ^ swz];

#pragma unroll
        for (int dt = 0; dt < NDT; ++dt) {
            const ushort* vr = Vtb + ((size_t)(dt * 16 + lr) << 10) + kt + lg * 8;
            bf16x8 bv0 = *(const bf16x8*)vr;
            bf16x8 bv1 = *(const bf16x8*)(vr + 32);
#pragma unroll
            for (int r = 0; r < 4; ++r) o[dt][r] *= fr[r];
            o[dt] = __builtin_amdgcn_mfma_f32_16x16x32_bf16(ap0, bv0, o[dt], 0, 0, 0);
            o[dt] = __builtin_amdgcn_mfma_f32_16x16x32_bf16(ap1, bv1, o[dt], 0, 0, 0);
        }
    }

    // ---- write ctx (fp32, unpadded layout) ----
#pragma unroll
    for (int r = 0; r < 4; ++r) {
        float inv = 1.0f / lrow[r];
        int q = q0 + wave * 16 + lg * 4 + r;
        float* dst = ctx + ((size_t)b * SEQ + q) * HID + s0;
#pragma unroll
        for (int dt = 0; dt < NDT; ++dt) {
            int dv = lr + 16 * dt;
            if (dv < d) dst[dv] = o[dt][r] * inv;
        }
    }
}

__global__ __launch_bounds__(256)
void attn_mfma(const ushort* __restrict__ qp, const ushort* __restrict__ kp,
               const ushort* __restrict__ vp, float* __restrict__ ctx)
{
    __shared__ ushort Ps[4][16][64];
    int wave = threadIdx.x >> 6;
    int h = blockIdx.y, b = blockIdx.z;
    int q0 = blockIdx.x * 64;
    if (h < 3)      attn_body<32>(qp, kp, vp, ctx, Ps[wave], h, b, q0);
    else if (h < 7) attn_body<64>(qp, kp, vp, ctx, Ps[wave], h, b, q0);
    else            attn_body<96>(qp, kp, vp, ctx, Ps[wave], h, b, q0);
}

// ---------------------------------------------------------------------------
extern "C" void kernel_launch(void* const* d_in, const int* in_sizes, int n_in,
                              void* d_out, int out_size, void* d_ws, size_t ws_size,
                              hipStream_t stream)
{
    const float* hs = (const float*)d_in[0];
    const float* Wq = (const float*)d_in[1];
    const float* bq = (const float*)d_in[2];
    const float* Wk = (const float*)d_in[3];
    const float* bk = (const float*)d_in[4];
    const float* Wv = (const float*)d_in[5];
    const float* bv = (const float*)d_in[6];
    const float* Wo = (const float*)d_in[7];
    const float* bo = (const float*)d_in[8];
    float* out = (float*)d_out;

    size_t pelem = (size_t)BATCH * PBE;            // 8,912,896 per tensor
    ushort* qp = (ushort*)d_ws;
    ushort* kp = qp + pelem;
    ushort* vp = kp + pelem;
    float* cbuf = (float*)(vp + pelem);            // fp32 ctx, 28.9 MB

    // zero qkv buffers so pad columns / pad dv-rows are exactly 0.0bf16
    hipMemsetAsync(d_ws, 0, 3 * pelem * sizeof(ushort), stream);

    int M = BATCH * SEQ;
    dim3 gg(M / 64, (HID + 63) / 64);              // 256 x 7

    gemm_bias<1><<<gg, 256, 0, stream>>>(hs, Wq, bq, qp, M, HID, HID);
    gemm_bias<1><<<gg, 256, 0, stream>>>(hs, Wk, bk, kp, M, HID, HID);
    gemm_bias<2><<<gg, 256, 0, stream>>>(hs, Wv, bv, vp, M, HID, HID);

    dim3 ga(SEQ / 64, NH, BATCH);                  // 16 x 9 x 16
    attn_mfma<<<ga, 256, 0, stream>>>(qp, kp, vp, cbuf);

    gemm_bias<0><<<gg, 256, 0, stream>>>(cbuf, Wo, bo, out, M, HID, HID);
}

// Round 6
// 411.465 us; speedup vs baseline: 10.8776x; 2.1665x over previous
//
#include <hip/hip_runtime.h>
#include <math.h>

#define BATCH 16
#define SEQ   1024
#define HID   441
#define NH    9
#define KP    448                 // padded hidden (K and N dim of GEMMs)
#define PB    544                 // sum of padded head dims
#define PBE   (SEQ * PB)          // padded elems per batch
#define WTS   (KP * KP)           // one transposed weight matrix

typedef __attribute__((ext_vector_type(8))) short bf16x8;
typedef __attribute__((ext_vector_type(4))) float f32x4;

__constant__ int c_bounds[NH + 1] = {0, 7, 21, 49, 105, 161, 217, 273, 357, 441};
__constant__ int c_dpad[NH] = {32, 32, 32, 64, 64, 64, 64, 96, 96};
__constant__ int c_cum[NH]  = {0, 32, 64, 96, 160, 224, 288, 352, 448};

__device__ __forceinline__ ushort f2bf(float x) {
    union { float f; unsigned u; } v; v.f = x;
    unsigned r = v.u + 0x7FFF + ((v.u >> 16) & 1);   // RNE
    return (ushort)(r >> 16);
}

__device__ __forceinline__ void gld_lds16(const ushort* g, ushort* l) {
    __builtin_amdgcn_global_load_lds(
        (const __attribute__((address_space(1))) unsigned int*)g,
        (__attribute__((address_space(3))) unsigned int*)l, 16, 0, 0);
}

// ---------------------------------------------------------------------------
// hs fp32 [16384][441] -> bf16 [16384][448] (pad cols zeroed)
// ---------------------------------------------------------------------------
__global__ __launch_bounds__(256)
void convert_hs(const float* __restrict__ hs, ushort* __restrict__ out)
{
    int t = blockIdx.x * 256 + threadIdx.x;   // 16384*56 threads
    int r = t / 56, cc = t % 56;
    const float* src = hs + (size_t)r * HID + cc * 8;
    union { ushort u[8]; bf16x8 v; } pk;
#pragma unroll
    for (int j = 0; j < 8; ++j) {
        int c = cc * 8 + j;
        pk.u[j] = (c < HID) ? f2bf(src[j]) : (ushort)0;
    }
    *(bf16x8*)(out + (size_t)r * KP + cc * 8) = pk.v;
}

// ---------------------------------------------------------------------------
// W fp32 [441][441] -> W^T bf16 [448][448] (pads zero). blockIdx.y = matrix.
// ---------------------------------------------------------------------------
__global__ __launch_bounds__(256)
void convert_w(const float* __restrict__ W0, const float* __restrict__ W1,
               const float* __restrict__ W2, const float* __restrict__ W3,
               ushort* __restrict__ wt)
{
    const float* W = (blockIdx.y == 0) ? W0 : (blockIdx.y == 1) ? W1
                   : (blockIdx.y == 2) ? W2 : W3;
    ushort* out = wt + (size_t)blockIdx.y * WTS;
    int t = blockIdx.x * 256 + threadIdx.x;   // 448*56 threads
    int n = t / 56, kc = t % 56;
    union { ushort u[8]; bf16x8 v; } pk;
#pragma unroll
    for (int j = 0; j < 8; ++j) {
        int k = kc * 8 + j;
        pk.u[j] = (k < HID && n < HID) ? f2bf(W[(size_t)k * HID + n]) : (ushort)0;
    }
    *(bf16x8*)(out + (size_t)n * KP + kc * 8) = pk.v;
}

// ---------------------------------------------------------------------------
// bf16 MFMA GEMM: C[16384, 448] = A[16384, 448] @ Bt[448, 448]^T + bias
// A row-major bf16 (padded), Bt = W^T row-major bf16 (so B-frag rows = out cols).
// Tile 128x64, BK=32, 4 waves (2x2), global_load_lds staging, 1 barrier/step.
// MODE 0: bf16 scatter -> padded [b][h][s][dp]   (Q, K)
// MODE 1: bf16 scatter -> transposed [b][h][dv][s]  (V)
// MODE 2: fp32 row-major [16384][441] + bias      (O)
// ---------------------------------------------------------------------------
template<int MODE>
__global__ __launch_bounds__(256)
void gemm_mfma(const ushort* __restrict__ A, const ushort* __restrict__ Bt,
               const float* __restrict__ bias, void* __restrict__ Cout)
{
    __shared__ ushort As[2][128 * 32];   // per buffer: 128 rows x 32 K = 4096 ushorts
    __shared__ ushort Bs[2][64 * 32];

    int tid = threadIdx.x;
    int wid = tid >> 6, lane = tid & 63;
    int wm = wid >> 1, wn = wid & 1;
    int lr = lane & 15, lg = lane >> 4;
    int m0 = blockIdx.x * 128, n0 = blockIdx.y * 64;

    const ushort* a_src = A + (size_t)(m0 + (tid >> 2)) * KP + (tid & 3) * 8;
    const ushort* b_src = Bt + (size_t)(n0 + (tid >> 2)) * KP + (tid & 3) * 8;

    f32x4 acc[4][2];
#pragma unroll
    for (int i = 0; i < 4; ++i)
#pragma unroll
        for (int j = 0; j < 2; ++j) acc[i][j] = (f32x4){0.f, 0.f, 0.f, 0.f};

    // stage K-chunk k0 into buffer buf.
    // rows 0..63 -> LDS ushort offset tid*8 (= row*32 + kcol)
    // rows 64..127 -> LDS ushort offset 2048 + tid*8   [R4 BUG: was 4096 -> OOB]
    auto stage = [&](int buf, int k0) {
        gld_lds16(a_src + k0,            &As[buf][tid * 8]);
        gld_lds16(a_src + 64 * KP + k0,  &As[buf][2048 + tid * 8]);
        gld_lds16(b_src + k0,            &Bs[buf][tid * 8]);
    };

    stage(0, 0);
#pragma unroll 2
    for (int t = 0; t < 14; ++t) {
        int buf = t & 1;
        __syncthreads();                       // drains vmcnt+lgkm: buf staged, prev reads done
        if (t < 13) stage(buf ^ 1, (t + 1) * 32);

        bf16x8 af[4], bf[2];
#pragma unroll
        for (int mr = 0; mr < 4; ++mr)
            af[mr] = *(const bf16x8*)&As[buf][(wm * 64 + mr * 16 + lr) * 32 + lg * 8];
#pragma unroll
        for (int nt = 0; nt < 2; ++nt)
            bf[nt] = *(const bf16x8*)&Bs[buf][(wn * 32 + nt * 16 + lr) * 32 + lg * 8];
#pragma unroll
        for (int mr = 0; mr < 4; ++mr)
#pragma unroll
            for (int nt = 0; nt < 2; ++nt)
                acc[mr][nt] = __builtin_amdgcn_mfma_f32_16x16x32_bf16(af[mr], bf[nt], acc[mr][nt], 0, 0, 0);
    }

    // ---- epilogue ----
    int bb = m0 >> 10;
    int srow = (m0 & 1023) + wm * 64;

#pragma unroll
    for (int nt = 0; nt < 2; ++nt) {
        int gn = n0 + wn * 32 + nt * 16 + lr;
        bool ok = gn < HID;
        int gcl = ok ? gn : 0;
        float bval = ok ? bias[gcl] : 0.f;
        int hh = 0;
        while (gcl >= c_bounds[hh + 1]) ++hh;
        int off = gcl - c_bounds[hh];
        int dph = c_dpad[hh];
        size_t hbase = (size_t)bb * PBE + ((size_t)c_cum[hh] << 10);

#pragma unroll
        for (int mr = 0; mr < 4; ++mr)
#pragma unroll
            for (int r = 0; r < 4; ++r) {
                if (!ok) continue;
                int s = srow + mr * 16 + lg * 4 + r;
                float val = acc[mr][nt][r] + bval;
                if (MODE == 0) {
                    ((ushort*)Cout)[hbase + (size_t)s * dph + off] = f2bf(val);
                } else if (MODE == 1) {
                    ((ushort*)Cout)[hbase + ((size_t)off << 10) + s] = f2bf(val);
                } else {
                    ((float*)Cout)[(size_t)(m0 + wm * 64 + mr * 16 + lg * 4 + r) * HID + gn] = val;
                }
            }
    }
}

// ---------------------------------------------------------------------------
// MFMA flash attention, KVBLK=128, barrier-free, XCD-grouped dispatch.
// Block = (b, h, 64 q-rows); 4 independent waves x 16 q-rows.
// Q[s][DP], K[s][DP] padded; V TRANSPOSED [dv][1024]; ctx bf16 [s][448].
// ---------------------------------------------------------------------------
template<int DP>
__device__ __forceinline__
void attn_body(const ushort* __restrict__ qp, const ushort* __restrict__ kp,
               const ushort* __restrict__ vp, ushort* __restrict__ ctx,
               ushort (* __restrict__ Ps)[128], int h, int b, int q0)
{
    constexpr int NDT = DP / 16;         // output col tiles (2/4/6)
    constexpr int NXC = DP / 32;         // K-dim chunks for QK (1/2/3)

    int lane = threadIdx.x & 63;
    int wave = threadIdx.x >> 6;
    int lr = lane & 15, lg = lane >> 4;

    int s0 = c_bounds[h];
    int d  = c_bounds[h + 1] - s0;
    float scale2 = rsqrtf((float)d) * 1.44269504089f;   // exp2 domain

    size_t base = (size_t)b * PBE + ((size_t)c_cum[h] << 10);
    const ushort* Q   = qp + base;
    const ushort* Kb  = kp + base;
    const ushort* Vtb = vp + base;

    int swz = (lr & 7) << 3;

    bf16x8 aq[NXC];
    {
        int qrow = q0 + wave * 16 + lr;
        const ushort* qr = Q + (size_t)qrow * DP + lg * 8;
#pragma unroll
        for (int xc = 0; xc < NXC; ++xc)
            aq[xc] = *(const bf16x8*)(qr + xc * 32);
    }

    f32x4 o[NDT];
#pragma unroll
    for (int i = 0; i < NDT; ++i) o[i] = (f32x4){0.f, 0.f, 0.f, 0.f};
    float mrow[4] = {-1e30f, -1e30f, -1e30f, -1e30f};
    float lrow[4] = {0.f, 0.f, 0.f, 0.f};

    for (int kt = 0; kt < SEQ; kt += 128) {
        // ---- S = Q K^T : 16 q x 128 keys per wave ----
        f32x4 sc[8];
#pragma unroll
        for (int ct = 0; ct < 8; ++ct) {
            f32x4 s = {0.f, 0.f, 0.f, 0.f};
            const ushort* kr = Kb + (size_t)(kt + ct * 16 + lr) * DP + lg * 8;
#pragma unroll
            for (int xc = 0; xc < NXC; ++xc) {
                bf16x8 bk = *(const bf16x8*)(kr + xc * 32);
                s = __builtin_amdgcn_mfma_f32_16x16x32_bf16(aq[xc], bk, s, 0, 0, 0);
            }
            sc[ct] = s * scale2;
        }

        // ---- online softmax ----
        float mnew[4], fr[4];
#pragma unroll
        for (int r = 0; r < 4; ++r) {
            float mx = sc[0][r];
#pragma unroll
            for (int ct = 1; ct < 8; ++ct) mx = fmaxf(mx, sc[ct][r]);
#pragma unroll
            for (int off = 1; off < 16; off <<= 1)
                mx = fmaxf(mx, __shfl_xor(mx, off));
            mnew[r] = fmaxf(mrow[r], mx);
            fr[r] = exp2f(mrow[r] - mnew[r]);
            mrow[r] = mnew[r];
        }
#pragma unroll
        for (int r = 0; r < 4; ++r) {
            int row = lg * 4 + r;
            int wsz = (row & 7) << 3;
            float sum = 0.f;
#pragma unroll
            for (int ct = 0; ct < 8; ++ct) {
                float p = exp2f(sc[ct][r] - mnew[r]);
                sum += p;
                Ps[row][(lr + ct * 16) ^ wsz] = f2bf(p);
            }
#pragma unroll
            for (int off = 1; off < 16; off <<= 1)
                sum += __shfl_xor(sum, off);
            lrow[r] = lrow[r] * fr[r] + sum;
        }

        // ---- O = fr*O + P V ----
        bf16x8 ap[4];
#pragma unroll
        for (int ks = 0; ks < 4; ++ks)
            ap[ks] = *(const bf16x8*)&Ps[lr][(ks * 32 + lg * 8) ^ swz];

#pragma unroll
        for (int dt = 0; dt < NDT; ++dt) {
            const ushort* vr = Vtb + ((size_t)(dt * 16 + lr) << 10) + kt + lg * 8;
#pragma unroll
            for (int r = 0; r < 4; ++r) o[dt][r] *= fr[r];
#pragma unroll
            for (int ks = 0; ks < 4; ++ks) {
                bf16x8 bv = *(const bf16x8*)(vr + ks * 32);
                o[dt] = __builtin_amdgcn_mfma_f32_16x16x32_bf16(ap[ks], bv, o[dt], 0, 0, 0);
            }
        }
    }

    // ---- write ctx (bf16, padded [s][448] layout) ----
#pragma unroll
    for (int r = 0; r < 4; ++r) {
        float inv = 1.0f / lrow[r];
        int q = q0 + wave * 16 + lg * 4 + r;
        ushort* dst = ctx + ((size_t)(b << 10) + q) * KP + s0;
#pragma unroll
        for (int dt = 0; dt < NDT; ++dt) {
            int dv = lr + 16 * dt;
            if (dv < d) dst[dv] = f2bf(o[dt][r] * inv);
        }
    }
}

__global__ __launch_bounds__(256)
void attn_mfma(const ushort* __restrict__ qp, const ushort* __restrict__ kp,
               const ushort* __restrict__ vp, ushort* __restrict__ ctx)
{
    __shared__ ushort Ps[4][16][128];
    int wave = threadIdx.x >> 6;
    // XCD-group swizzle: all 16 q-tiles of one (b,h) land on one XCD
    // (assumes block i -> XCD i%8 round-robin; affects locality only)
    int i = blockIdx.x;
    int xcd = i & 7, slot = i >> 3;          // 288 slots per XCD
    int group = xcd + 8 * (slot >> 4);       // 0..143 bijective
    int sub = slot & 15;
    int b = group / NH, h = group % NH;
    int q0 = sub * 64;
    if (h < 3)      attn_body<32>(qp, kp, vp, ctx, Ps[wave], h, b, q0);
    else if (h < 7) attn_body<64>(qp, kp, vp, ctx, Ps[wave], h, b, q0);
    else            attn_body<96>(qp, kp, vp, ctx, Ps[wave], h, b, q0);
}

// ---------------------------------------------------------------------------
extern "C" void kernel_launch(void* const* d_in, const int* in_sizes, int n_in,
                              void* d_out, int out_size, void* d_ws, size_t ws_size,
                              hipStream_t stream)
{
    const float* hs = (const float*)d_in[0];
    const float* Wq = (const float*)d_in[1];
    const float* bq = (const float*)d_in[2];
    const float* Wk = (const float*)d_in[3];
    const float* bk = (const float*)d_in[4];
    const float* Wv = (const float*)d_in[5];
    const float* bv = (const float*)d_in[6];
    const float* Wo = (const float*)d_in[7];
    const float* bo = (const float*)d_in[8];

    size_t pelem = (size_t)BATCH * PBE;            // 8,912,896 per tensor
    ushort* qp  = (ushort*)d_ws;
    ushort* kp  = qp + pelem;
    ushort* vp  = kp + pelem;
    ushort* ctx = vp + pelem;                      // bf16 [16384][448]
    ushort* wt  = ctx + (size_t)BATCH * SEQ * KP;  // 4 x [448][448] bf16
    ushort* hsb = (ushort*)d_out;                  // bf16 hs, dead before final GEMM writes

    // zero q/k/v pads + ctx pad cols (contiguous region)
    hipMemsetAsync(d_ws, 0, (3 * pelem + (size_t)BATCH * SEQ * KP) * sizeof(ushort), stream);

    convert_hs<<<BATCH * SEQ * 56 / 256, 256, 0, stream>>>(hs, hsb);
    convert_w<<<dim3(KP * 56 / 256, 4), 256, 0, stream>>>(Wq, Wk, Wv, Wo, wt);

    dim3 gg(BATCH * SEQ / 128, KP / 64);           // 128 x 7
    gemm_mfma<0><<<gg, 256, 0, stream>>>(hsb, wt + 0 * (size_t)WTS, bq, qp);
    gemm_mfma<0><<<gg, 256, 0, stream>>>(hsb, wt + 1 * (size_t)WTS, bk, kp);
    gemm_mfma<1><<<gg, 256, 0, stream>>>(hsb, wt + 2 * (size_t)WTS, bv, vp);

    attn_mfma<<<SEQ / 64 * NH * BATCH, 256, 0, stream>>>(qp, kp, vp, ctx);

    gemm_mfma<2><<<gg, 256, 0, stream>>>(ctx, wt + 3 * (size_t)WTS, bo, d_out);
}

// Round 7
// 376.640 us; speedup vs baseline: 11.8833x; 1.0925x over previous
//
#include <hip/hip_runtime.h>
#include <math.h>

#define BATCH 16
#define SEQ   1024
#define HID   441
#define NH    9
#define KP    448                 // padded hidden (K and N dim of GEMMs)
#define PB    544                 // sum of padded head dims
#define PBE   (SEQ * PB)          // padded elems per batch
#define WTS   (KP * KP)           // one transposed weight matrix

typedef __attribute__((ext_vector_type(8))) short bf16x8;
typedef __attribute__((ext_vector_type(4))) float f32x4;

__constant__ int c_bounds[NH + 1] = {0, 7, 21, 49, 105, 161, 217, 273, 357, 441};
__constant__ int c_dpad[NH] = {32, 32, 32, 64, 64, 64, 64, 96, 96};
__constant__ int c_cum[NH]  = {0, 32, 64, 96, 160, 224, 288, 352, 448};

__device__ __forceinline__ ushort f2bf(float x) {
    union { float f; unsigned u; } v; v.f = x;
    unsigned r = v.u + 0x7FFF + ((v.u >> 16) & 1);   // RNE
    return (ushort)(r >> 16);
}

__device__ __forceinline__ void gld_lds16(const ushort* g, ushort* l) {
    __builtin_amdgcn_global_load_lds(
        (const __attribute__((address_space(1))) unsigned int*)g,
        (__attribute__((address_space(3))) unsigned int*)l, 16, 0, 0);
}

// ---------------------------------------------------------------------------
// hs fp32 [16384][441] -> bf16 [16384][448] (pad cols zeroed)
// ---------------------------------------------------------------------------
__global__ __launch_bounds__(256)
void convert_hs(const float* __restrict__ hs, ushort* __restrict__ out)
{
    int t = blockIdx.x * 256 + threadIdx.x;   // 16384*56 threads
    int r = t / 56, cc = t % 56;
    const float* src = hs + (size_t)r * HID + cc * 8;
    union { ushort u[8]; bf16x8 v; } pk;
#pragma unroll
    for (int j = 0; j < 8; ++j) {
        int c = cc * 8 + j;
        pk.u[j] = (c < HID) ? f2bf(src[j]) : (ushort)0;
    }
    *(bf16x8*)(out + (size_t)r * KP + cc * 8) = pk.v;
}

// ---------------------------------------------------------------------------
// W fp32 [441][441] -> W^T bf16 [448][448] (pads zero). blockIdx.y = matrix.
// ---------------------------------------------------------------------------
__global__ __launch_bounds__(256)
void convert_w(const float* __restrict__ W0, const float* __restrict__ W1,
               const float* __restrict__ W2, const float* __restrict__ W3,
               ushort* __restrict__ wt)
{
    const float* W = (blockIdx.y == 0) ? W0 : (blockIdx.y == 1) ? W1
                   : (blockIdx.y == 2) ? W2 : W3;
    ushort* out = wt + (size_t)blockIdx.y * WTS;
    int t = blockIdx.x * 256 + threadIdx.x;   // 448*56 threads
    int n = t / 56, kc = t % 56;
    union { ushort u[8]; bf16x8 v; } pk;
#pragma unroll
    for (int j = 0; j < 8; ++j) {
        int k = kc * 8 + j;
        pk.u[j] = (k < HID && n < HID) ? f2bf(W[(size_t)k * HID + n]) : (ushort)0;
    }
    *(bf16x8*)(out + (size_t)n * KP + kc * 8) = pk.v;
}

// ---------------------------------------------------------------------------
// bf16 MFMA GEMM: C[16384, 448] = A[16384, 448] @ Bt[448, 448]^T + bias
// Tile 128x64, BK=32, 4 waves (2x2), global_load_lds staging, 1 barrier/step.
// MODE 0: bf16 scatter -> padded [b][h][s][dp]   (Q, K)
// MODE 1: bf16 scatter -> transposed [b][h][dv][s]  (V)
// MODE 2: fp32 row-major [16384][441] + bias      (O)
// ---------------------------------------------------------------------------
template<int MODE>
__global__ __launch_bounds__(256)
void gemm_mfma(const ushort* __restrict__ A, const ushort* __restrict__ Bt,
               const float* __restrict__ bias, void* __restrict__ Cout)
{
    __shared__ ushort As[2][128 * 32];   // per buffer: 128 rows x 32 K = 4096 ushorts
    __shared__ ushort Bs[2][64 * 32];

    int tid = threadIdx.x;
    int wid = tid >> 6, lane = tid & 63;
    int wm = wid >> 1, wn = wid & 1;
    int lr = lane & 15, lg = lane >> 4;
    int m0 = blockIdx.x * 128, n0 = blockIdx.y * 64;

    const ushort* a_src = A + (size_t)(m0 + (tid >> 2)) * KP + (tid & 3) * 8;
    const ushort* b_src = Bt + (size_t)(n0 + (tid >> 2)) * KP + (tid & 3) * 8;

    f32x4 acc[4][2];
#pragma unroll
    for (int i = 0; i < 4; ++i)
#pragma unroll
        for (int j = 0; j < 2; ++j) acc[i][j] = (f32x4){0.f, 0.f, 0.f, 0.f};

    auto stage = [&](int buf, int k0) {
        gld_lds16(a_src + k0,            &As[buf][tid * 8]);
        gld_lds16(a_src + 64 * KP + k0,  &As[buf][2048 + tid * 8]);
        gld_lds16(b_src + k0,            &Bs[buf][tid * 8]);
    };

    stage(0, 0);
#pragma unroll 2
    for (int t = 0; t < 14; ++t) {
        int buf = t & 1;
        __syncthreads();                       // drains vmcnt+lgkm: buf staged, prev reads done
        if (t < 13) stage(buf ^ 1, (t + 1) * 32);

        bf16x8 af[4], bf[2];
#pragma unroll
        for (int mr = 0; mr < 4; ++mr)
            af[mr] = *(const bf16x8*)&As[buf][(wm * 64 + mr * 16 + lr) * 32 + lg * 8];
#pragma unroll
        for (int nt = 0; nt < 2; ++nt)
            bf[nt] = *(const bf16x8*)&Bs[buf][(wn * 32 + nt * 16 + lr) * 32 + lg * 8];
#pragma unroll
        for (int mr = 0; mr < 4; ++mr)
#pragma unroll
            for (int nt = 0; nt < 2; ++nt)
                acc[mr][nt] = __builtin_amdgcn_mfma_f32_16x16x32_bf16(af[mr], bf[nt], acc[mr][nt], 0, 0, 0);
    }

    // ---- epilogue ----
    int bb = m0 >> 10;
    int srow = (m0 & 1023) + wm * 64;

#pragma unroll
    for (int nt = 0; nt < 2; ++nt) {
        int gn = n0 + wn * 32 + nt * 16 + lr;
        bool ok = gn < HID;
        int gcl = ok ? gn : 0;
        float bval = ok ? bias[gcl] : 0.f;
        int hh = 0;
        while (gcl >= c_bounds[hh + 1]) ++hh;
        int off = gcl - c_bounds[hh];
        int dph = c_dpad[hh];
        size_t hbase = (size_t)bb * PBE + ((size_t)c_cum[hh] << 10);

#pragma unroll
        for (int mr = 0; mr < 4; ++mr)
#pragma unroll
            for (int r = 0; r < 4; ++r) {
                if (!ok) continue;
                int s = srow + mr * 16 + lg * 4 + r;
                float val = acc[mr][nt][r] + bval;
                if (MODE == 0) {
                    ((ushort*)Cout)[hbase + (size_t)s * dph + off] = f2bf(val);
                } else if (MODE == 1) {
                    ((ushort*)Cout)[hbase + ((size_t)off << 10) + s] = f2bf(val);
                } else {
                    ((float*)Cout)[(size_t)(m0 + wm * 64 + mr * 16 + lg * 4 + r) * HID + gn] = val;
                }
            }
    }
}

// ---------------------------------------------------------------------------
// MFMA flash attention, KVBLK=128, SINGLE-WAVE workgroups (64 threads).
// Block = (b, h, 16 q-rows). 16 WGs/CU resident -> 4 waves/SIMD (VGPR<=128).
// Q[s][DP], K[s][DP] padded; V TRANSPOSED [dv][1024]; ctx bf16 [s][448].
// s_setprio around MFMA clusters (T5 — independent 1-wave blocks, m191).
// ---------------------------------------------------------------------------
template<int DP>
__device__ __forceinline__
void attn_body(const ushort* __restrict__ qp, const ushort* __restrict__ kp,
               const ushort* __restrict__ vp, ushort* __restrict__ ctx,
               ushort (* __restrict__ Ps)[128], int h, int b, int q0)
{
    constexpr int NDT = DP / 16;         // output col tiles (2/4/6)
    constexpr int NXC = DP / 32;         // K-dim chunks for QK (1/2/3)

    int lane = threadIdx.x & 63;
    int lr = lane & 15, lg = lane >> 4;

    int s0 = c_bounds[h];
    int d  = c_bounds[h + 1] - s0;
    float scale2 = rsqrtf((float)d) * 1.44269504089f;   // exp2 domain

    size_t base = (size_t)b * PBE + ((size_t)c_cum[h] << 10);
    const ushort* Q   = qp + base;
    const ushort* Kb  = kp + base;
    const ushort* Vtb = vp + base;

    int swz = (lr & 7) << 3;

    bf16x8 aq[NXC];
    {
        int qrow = q0 + lr;
        const ushort* qr = Q + (size_t)qrow * DP + lg * 8;
#pragma unroll
        for (int xc = 0; xc < NXC; ++xc)
            aq[xc] = *(const bf16x8*)(qr + xc * 32);
    }

    f32x4 o[NDT];
#pragma unroll
    for (int i = 0; i < NDT; ++i) o[i] = (f32x4){0.f, 0.f, 0.f, 0.f};
    float mrow[4] = {-1e30f, -1e30f, -1e30f, -1e30f};
    float lrow[4] = {0.f, 0.f, 0.f, 0.f};

    for (int kt = 0; kt < SEQ; kt += 128) {
        // ---- S = Q K^T : 16 q x 128 keys ----
        f32x4 sc[8];
        __builtin_amdgcn_s_setprio(1);
#pragma unroll
        for (int ct = 0; ct < 8; ++ct) {
            f32x4 s = {0.f, 0.f, 0.f, 0.f};
            const ushort* kr = Kb + (size_t)(kt + ct * 16 + lr) * DP + lg * 8;
#pragma unroll
            for (int xc = 0; xc < NXC; ++xc) {
                bf16x8 bk = *(const bf16x8*)(kr + xc * 32);
                s = __builtin_amdgcn_mfma_f32_16x16x32_bf16(aq[xc], bk, s, 0, 0, 0);
            }
            sc[ct] = s * scale2;
        }
        __builtin_amdgcn_s_setprio(0);

        // ---- online softmax ----
        float mnew[4], fr[4];
#pragma unroll
        for (int r = 0; r < 4; ++r) {
            float mx = sc[0][r];
#pragma unroll
            for (int ct = 1; ct < 8; ++ct) mx = fmaxf(mx, sc[ct][r]);
#pragma unroll
            for (int off = 1; off < 16; off <<= 1)
                mx = fmaxf(mx, __shfl_xor(mx, off));
            mnew[r] = fmaxf(mrow[r], mx);
            fr[r] = exp2f(mrow[r] - mnew[r]);
            mrow[r] = mnew[r];
        }
#pragma unroll
        for (int r = 0; r < 4; ++r) {
            int row = lg * 4 + r;
            int wsz = (row & 7) << 3;
            float sum = 0.f;
#pragma unroll
            for (int ct = 0; ct < 8; ++ct) {
                float p = exp2f(sc[ct][r] - mnew[r]);
                sum += p;
                Ps[row][(lr + ct * 16) ^ wsz] = f2bf(p);
            }
#pragma unroll
            for (int off = 1; off < 16; off <<= 1)
                sum += __shfl_xor(sum, off);
            lrow[r] = lrow[r] * fr[r] + sum;
        }

        // ---- O = fr*O + P V ----
        bf16x8 ap[4];
#pragma unroll
        for (int ks = 0; ks < 4; ++ks)
            ap[ks] = *(const bf16x8*)&Ps[lr][(ks * 32 + lg * 8) ^ swz];

        __builtin_amdgcn_s_setprio(1);
#pragma unroll
        for (int dt = 0; dt < NDT; ++dt) {
            const ushort* vr = Vtb + ((size_t)(dt * 16 + lr) << 10) + kt + lg * 8;
#pragma unroll
            for (int r = 0; r < 4; ++r) o[dt][r] *= fr[r];
#pragma unroll
            for (int ks = 0; ks < 4; ++ks) {
                bf16x8 bv = *(const bf16x8*)(vr + ks * 32);
                o[dt] = __builtin_amdgcn_mfma_f32_16x16x32_bf16(ap[ks], bv, o[dt], 0, 0, 0);
            }
        }
        __builtin_amdgcn_s_setprio(0);
    }

    // ---- write ctx (bf16, padded [s][448] layout) ----
#pragma unroll
    for (int r = 0; r < 4; ++r) {
        float inv = 1.0f / lrow[r];
        int q = q0 + lg * 4 + r;
        ushort* dst = ctx + ((size_t)(b << 10) + q) * KP + s0;
#pragma unroll
        for (int dt = 0; dt < NDT; ++dt) {
            int dv = lr + 16 * dt;
            if (dv < d) dst[dv] = f2bf(o[dt][r] * inv);
        }
    }
}

__global__ __launch_bounds__(64, 4)
void attn_mfma(const ushort* __restrict__ qp, const ushort* __restrict__ kp,
               const ushort* __restrict__ vp, ushort* __restrict__ ctx)
{
    __shared__ ushort Ps[16][128];           // 4 KB / single-wave workgroup
    // XCD-group swizzle: all 64 q-tiles of one (b,h) land on one XCD
    // (9216 blocks = 8 xcd x 1152; 144 groups = 8 x 18 — bijective)
    int i = blockIdx.x;
    int xcd = i & 7, slot = i >> 3;          // slot 0..1151
    int group = xcd + 8 * (slot >> 6);       // 0..143
    int sub = slot & 63;                     // q-tile within group
    int b = group / NH, h = group % NH;
    int q0 = sub * 16;
    if (h < 3)      attn_body<32>(qp, kp, vp, ctx, Ps, h, b, q0);
    else if (h < 7) attn_body<64>(qp, kp, vp, ctx, Ps, h, b, q0);
    else            attn_body<96>(qp, kp, vp, ctx, Ps, h, b, q0);
}

// ---------------------------------------------------------------------------
extern "C" void kernel_launch(void* const* d_in, const int* in_sizes, int n_in,
                              void* d_out, int out_size, void* d_ws, size_t ws_size,
                              hipStream_t stream)
{
    const float* hs = (const float*)d_in[0];
    const float* Wq = (const float*)d_in[1];
    const float* bq = (const float*)d_in[2];
    const float* Wk = (const float*)d_in[3];
    const float* bk = (const float*)d_in[4];
    const float* Wv = (const float*)d_in[5];
    const float* bv = (const float*)d_in[6];
    const float* Wo = (const float*)d_in[7];
    const float* bo = (const float*)d_in[8];

    size_t pelem = (size_t)BATCH * PBE;            // 8,912,896 per tensor
    ushort* qp  = (ushort*)d_ws;
    ushort* kp  = qp + pelem;
    ushort* vp  = kp + pelem;
    ushort* ctx = vp + pelem;                      // bf16 [16384][448]
    ushort* wt  = ctx + (size_t)BATCH * SEQ * KP;  // 4 x [448][448] bf16
    ushort* hsb = (ushort*)d_out;                  // bf16 hs, dead before final GEMM writes

    // zero q/k/v pads + ctx pad cols (contiguous region)
    hipMemsetAsync(d_ws, 0, (3 * pelem + (size_t)BATCH * SEQ * KP) * sizeof(ushort), stream);

    convert_hs<<<BATCH * SEQ * 56 / 256, 256, 0, stream>>>(hs, hsb);
    convert_w<<<dim3(KP * 56 / 256, 4), 256, 0, stream>>>(Wq, Wk, Wv, Wo, wt);

    dim3 gg(BATCH * SEQ / 128, KP / 64);           // 128 x 7
    gemm_mfma<0><<<gg, 256, 0, stream>>>(hsb, wt + 0 * (size_t)WTS, bq, qp);
    gemm_mfma<0><<<gg, 256, 0, stream>>>(hsb, wt + 1 * (size_t)WTS, bk, kp);
    gemm_mfma<1><<<gg, 256, 0, stream>>>(hsb, wt + 2 * (size_t)WTS, bv, vp);

    attn_mfma<<<SEQ / 16 * NH * BATCH, 64, 0, stream>>>(qp, kp, vp, ctx);

    gemm_mfma<2><<<gg, 256, 0, stream>>>(ctx, wt + 3 * (size_t)WTS, bo, d_out);
}

// Round 8
// 375.776 us; speedup vs baseline: 11.9106x; 1.0023x over previous
//
#include <hip/hip_runtime.h>
#include <math.h>

#define BATCH 16
#define SEQ   1024
#define HID   441
#define NH    9
#define KP    448                 // padded hidden (K and N dim of GEMMs)
#define PB    544                 // sum of padded head dims
#define PBE   (SEQ * PB)          // padded elems per batch
#define WTS   (KP * KP)           // one transposed weight matrix

typedef __attribute__((ext_vector_type(8))) short bf16x8;
typedef __attribute__((ext_vector_type(4))) float f32x4;

__constant__ int c_bounds[NH + 1] = {0, 7, 21, 49, 105, 161, 217, 273, 357, 441};
__constant__ int c_dpad[NH] = {32, 32, 32, 64, 64, 64, 64, 96, 96};
__constant__ int c_cum[NH]  = {0, 32, 64, 96, 160, 224, 288, 352, 448};

__device__ __forceinline__ ushort f2bf(float x) {
    union { float f; unsigned u; } v; v.f = x;
    unsigned r = v.u + 0x7FFF + ((v.u >> 16) & 1);   // RNE
    return (ushort)(r >> 16);
}

__device__ __forceinline__ void gld_lds16(const ushort* g, ushort* l) {
    __builtin_amdgcn_global_load_lds(
        (const __attribute__((address_space(1))) unsigned int*)g,
        (__attribute__((address_space(3))) unsigned int*)l, 16, 0, 0);
}

// ---------------------------------------------------------------------------
// hs fp32 [16384][441] -> bf16 [16384][448] (pad cols zeroed)
// ---------------------------------------------------------------------------
__global__ __launch_bounds__(256)
void convert_hs(const float* __restrict__ hs, ushort* __restrict__ out)
{
    int t = blockIdx.x * 256 + threadIdx.x;   // 16384*56 threads
    int r = t / 56, cc = t % 56;
    const float* src = hs + (size_t)r * HID + cc * 8;
    union { ushort u[8]; bf16x8 v; } pk;
#pragma unroll
    for (int j = 0; j < 8; ++j) {
        int c = cc * 8 + j;
        pk.u[j] = (c < HID) ? f2bf(src[j]) : (ushort)0;
    }
    *(bf16x8*)(out + (size_t)r * KP + cc * 8) = pk.v;
}

// ---------------------------------------------------------------------------
// W fp32 [441][441] -> W^T bf16 [448][448] (pads zero). blockIdx.y = matrix.
// ---------------------------------------------------------------------------
__global__ __launch_bounds__(256)
void convert_w(const float* __restrict__ W0, const float* __restrict__ W1,
               const float* __restrict__ W2, const float* __restrict__ W3,
               ushort* __restrict__ wt)
{
    const float* W = (blockIdx.y == 0) ? W0 : (blockIdx.y == 1) ? W1
                   : (blockIdx.y == 2) ? W2 : W3;
    ushort* out = wt + (size_t)blockIdx.y * WTS;
    int t = blockIdx.x * 256 + threadIdx.x;   // 448*56 threads
    int n = t / 56, kc = t % 56;
    union { ushort u[8]; bf16x8 v; } pk;
#pragma unroll
    for (int j = 0; j < 8; ++j) {
        int k = kc * 8 + j;
        pk.u[j] = (k < HID && n < HID) ? f2bf(W[(size_t)k * HID + n]) : (ushort)0;
    }
    *(bf16x8*)(out + (size_t)n * KP + kc * 8) = pk.v;
}

// ---------------------------------------------------------------------------
// bf16 MFMA GEMM: C[16384, 448] = A[16384, 448] @ Bt[448, 448]^T + bias
// Tile 128x64, BK=32, 4 waves (2x2), global_load_lds staging, 1 barrier/step.
// MODE 0: Q — bf16 scatter -> padded [b][h][s][dp], PRE-SCALED by log2e/sqrt(d)
// MODE 3: K — bf16 scatter -> padded [b][h][s][dp], unscaled
// MODE 1: V — bf16 scatter -> transposed [b][h][dv][s]
// MODE 2: O — fp32 row-major [16384][441] + bias
// ---------------------------------------------------------------------------
template<int MODE>
__global__ __launch_bounds__(256)
void gemm_mfma(const ushort* __restrict__ A, const ushort* __restrict__ Bt,
               const float* __restrict__ bias, void* __restrict__ Cout)
{
    __shared__ ushort As[2][128 * 32];   // per buffer: 128 rows x 32 K = 4096 ushorts
    __shared__ ushort Bs[2][64 * 32];

    int tid = threadIdx.x;
    int wid = tid >> 6, lane = tid & 63;
    int wm = wid >> 1, wn = wid & 1;
    int lr = lane & 15, lg = lane >> 4;
    int m0 = blockIdx.x * 128, n0 = blockIdx.y * 64;

    const ushort* a_src = A + (size_t)(m0 + (tid >> 2)) * KP + (tid & 3) * 8;
    const ushort* b_src = Bt + (size_t)(n0 + (tid >> 2)) * KP + (tid & 3) * 8;

    f32x4 acc[4][2];
#pragma unroll
    for (int i = 0; i < 4; ++i)
#pragma unroll
        for (int j = 0; j < 2; ++j) acc[i][j] = (f32x4){0.f, 0.f, 0.f, 0.f};

    auto stage = [&](int buf, int k0) {
        gld_lds16(a_src + k0,            &As[buf][tid * 8]);
        gld_lds16(a_src + 64 * KP + k0,  &As[buf][2048 + tid * 8]);
        gld_lds16(b_src + k0,            &Bs[buf][tid * 8]);
    };

    stage(0, 0);
#pragma unroll 2
    for (int t = 0; t < 14; ++t) {
        int buf = t & 1;
        __syncthreads();                       // drains vmcnt+lgkm: buf staged, prev reads done
        if (t < 13) stage(buf ^ 1, (t + 1) * 32);

        bf16x8 af[4], bf[2];
#pragma unroll
        for (int mr = 0; mr < 4; ++mr)
            af[mr] = *(const bf16x8*)&As[buf][(wm * 64 + mr * 16 + lr) * 32 + lg * 8];
#pragma unroll
        for (int nt = 0; nt < 2; ++nt)
            bf[nt] = *(const bf16x8*)&Bs[buf][(wn * 32 + nt * 16 + lr) * 32 + lg * 8];
#pragma unroll
        for (int mr = 0; mr < 4; ++mr)
#pragma unroll
            for (int nt = 0; nt < 2; ++nt)
                acc[mr][nt] = __builtin_amdgcn_mfma_f32_16x16x32_bf16(af[mr], bf[nt], acc[mr][nt], 0, 0, 0);
    }

    // ---- epilogue ----
    int bb = m0 >> 10;
    int srow = (m0 & 1023) + wm * 64;

#pragma unroll
    for (int nt = 0; nt < 2; ++nt) {
        int gn = n0 + wn * 32 + nt * 16 + lr;
        bool ok = gn < HID;
        int gcl = ok ? gn : 0;
        float bval = ok ? bias[gcl] : 0.f;
        int hh = 0;
        while (gcl >= c_bounds[hh + 1]) ++hh;
        int off = gcl - c_bounds[hh];
        int dph = c_dpad[hh];
        size_t hbase = (size_t)bb * PBE + ((size_t)c_cum[hh] << 10);
        // Q pre-scale: fold log2e / sqrt(d) into Q so attention needs no score mul
        float cs = (MODE == 0)
                 ? rsqrtf((float)(c_bounds[hh + 1] - c_bounds[hh])) * 1.44269504f
                 : 1.0f;

#pragma unroll
        for (int mr = 0; mr < 4; ++mr)
#pragma unroll
            for (int r = 0; r < 4; ++r) {
                if (!ok) continue;
                int s = srow + mr * 16 + lg * 4 + r;
                float val = (acc[mr][nt][r] + bval) * cs;
                if (MODE == 0 || MODE == 3) {
                    ((ushort*)Cout)[hbase + (size_t)s * dph + off] = f2bf(val);
                } else if (MODE == 1) {
                    ((ushort*)Cout)[hbase + ((size_t)off << 10) + s] = f2bf(val);
                } else {
                    ((float*)Cout)[(size_t)(m0 + wm * 64 + mr * 16 + lg * 4 + r) * HID + gn] = val;
                }
            }
    }
}

// ---------------------------------------------------------------------------
// MFMA flash attention, KVBLK=128, 2-wave workgroups (128 thr, barrier-free;
// waves fully independent, per-wave Ps). 16 WG/CU x 2 waves -> up to 100% occ.
// Q pre-scaled (exp2 domain); K[s][DP] padded; V TRANSPOSED [dv][1024].
// ---------------------------------------------------------------------------
template<int DP>
__device__ __forceinline__
void attn_body(const ushort* __restrict__ qp, const ushort* __restrict__ kp,
               const ushort* __restrict__ vp, ushort* __restrict__ ctx,
               ushort (* __restrict__ Ps)[128], int h, int b, int q0)
{
    constexpr int NDT = DP / 16;         // output col tiles (2/4/6)
    constexpr int NXC = DP / 32;         // K-dim chunks for QK (1/2/3)

    int lane = threadIdx.x & 63;
    int lr = lane & 15, lg = lane >> 4;

    int s0 = c_bounds[h];
    int d  = c_bounds[h + 1] - s0;

    size_t base = (size_t)b * PBE + ((size_t)c_cum[h] << 10);
    const ushort* Q   = qp + base;
    const ushort* Kb  = kp + base;
    const ushort* Vtb = vp + base;

    int swz = (lr & 7) << 3;

    bf16x8 aq[NXC];
    {
        int qrow = q0 + lr;
        const ushort* qr = Q + (size_t)qrow * DP + lg * 8;
#pragma unroll
        for (int xc = 0; xc < NXC; ++xc)
            aq[xc] = *(const bf16x8*)(qr + xc * 32);
    }

    f32x4 o[NDT];
#pragma unroll
    for (int i = 0; i < NDT; ++i) o[i] = (f32x4){0.f, 0.f, 0.f, 0.f};
    float mrow[4] = {-1e30f, -1e30f, -1e30f, -1e30f};
    float lrow[4] = {0.f, 0.f, 0.f, 0.f};

    for (int kt = 0; kt < SEQ; kt += 128) {
        // ---- S = Q K^T : 16 q x 128 keys (already exp2-scaled via Q) ----
        f32x4 sc[8];
        __builtin_amdgcn_s_setprio(1);
#pragma unroll
        for (int ct = 0; ct < 8; ++ct) {
            f32x4 s = {0.f, 0.f, 0.f, 0.f};
            const ushort* kr = Kb + (size_t)(kt + ct * 16 + lr) * DP + lg * 8;
#pragma unroll
            for (int xc = 0; xc < NXC; ++xc) {
                bf16x8 bk = *(const bf16x8*)(kr + xc * 32);
                s = __builtin_amdgcn_mfma_f32_16x16x32_bf16(aq[xc], bk, s, 0, 0, 0);
            }
            sc[ct] = s;
        }
        __builtin_amdgcn_s_setprio(0);

        // ---- online softmax ----
        float mnew[4], fr[4];
#pragma unroll
        for (int r = 0; r < 4; ++r) {
            float mx = sc[0][r];
#pragma unroll
            for (int ct = 1; ct < 8; ++ct) mx = fmaxf(mx, sc[ct][r]);
#pragma unroll
            for (int off = 1; off < 16; off <<= 1)
                mx = fmaxf(mx, __shfl_xor(mx, off));
            mnew[r] = fmaxf(mrow[r], mx);
            fr[r] = exp2f(mrow[r] - mnew[r]);
            mrow[r] = mnew[r];
        }
#pragma unroll
        for (int r = 0; r < 4; ++r) {
            int row = lg * 4 + r;
            int wsz = (row & 7) << 3;
            float sum = 0.f;
#pragma unroll
            for (int ct = 0; ct < 8; ++ct) {
                float p = exp2f(sc[ct][r] - mnew[r]);
                sum += p;
                // round-half-up bf16 (2 VALU ops; no systematic bias)
                Ps[row][(lr + ct * 16) ^ wsz] =
                    (ushort)((__builtin_bit_cast(unsigned, p) + 0x8000u) >> 16);
            }
#pragma unroll
            for (int off = 1; off < 16; off <<= 1)
                sum += __shfl_xor(sum, off);
            lrow[r] = lrow[r] * fr[r] + sum;
        }

        // ---- O = fr*O + P V ----
        bf16x8 ap[4];
#pragma unroll
        for (int ks = 0; ks < 4; ++ks)
            ap[ks] = *(const bf16x8*)&Ps[lr][(ks * 32 + lg * 8) ^ swz];

        __builtin_amdgcn_s_setprio(1);
#pragma unroll
        for (int dt = 0; dt < NDT; ++dt) {
            const ushort* vr = Vtb + ((size_t)(dt * 16 + lr) << 10) + kt + lg * 8;
#pragma unroll
            for (int r = 0; r < 4; ++r) o[dt][r] *= fr[r];
#pragma unroll
            for (int ks = 0; ks < 4; ++ks) {
                bf16x8 bv = *(const bf16x8*)(vr + ks * 32);
                o[dt] = __builtin_amdgcn_mfma_f32_16x16x32_bf16(ap[ks], bv, o[dt], 0, 0, 0);
            }
        }
        __builtin_amdgcn_s_setprio(0);
    }

    // ---- write ctx (bf16, padded [s][448] layout) ----
#pragma unroll
    for (int r = 0; r < 4; ++r) {
        float inv = 1.0f / lrow[r];
        int q = q0 + lg * 4 + r;
        ushort* dst = ctx + ((size_t)(b << 10) + q) * KP + s0;
#pragma unroll
        for (int dt = 0; dt < NDT; ++dt) {
            int dv = lr + 16 * dt;
            if (dv < d) dst[dv] = f2bf(o[dt][r] * inv);
        }
    }
}

__global__ __launch_bounds__(128, 4)
void attn_mfma(const ushort* __restrict__ qp, const ushort* __restrict__ kp,
               const ushort* __restrict__ vp, ushort* __restrict__ ctx)
{
    __shared__ ushort Ps[2][16][128];        // 8 KB / 2-wave workgroup
    int wave = threadIdx.x >> 6;
    // XCD-group swizzle: all 32 WGs of one (b,h) land on one XCD.
    // 4608 WGs = 8 xcd x 576 slots; 144 groups = 8 x 18 — bijective.
    int i = blockIdx.x;
    int xcd = i & 7, slot = i >> 3;          // slot 0..575
    int group = xcd + 8 * (slot >> 5);       // 0..143
    int sub = slot & 31;                     // 32-row tile within group
    int b = group / NH, h = group % NH;
    int q0 = sub * 32 + wave * 16;
    if (h < 3)      attn_body<32>(qp, kp, vp, ctx, Ps[wave], h, b, q0);
    else if (h < 7) attn_body<64>(qp, kp, vp, ctx, Ps[wave], h, b, q0);
    else            attn_body<96>(qp, kp, vp, ctx, Ps[wave], h, b, q0);
}

// ---------------------------------------------------------------------------
extern "C" void kernel_launch(void* const* d_in, const int* in_sizes, int n_in,
                              void* d_out, int out_size, void* d_ws, size_t ws_size,
                              hipStream_t stream)
{
    const float* hs = (const float*)d_in[0];
    const float* Wq = (const float*)d_in[1];
    const float* bq = (const float*)d_in[2];
    const float* Wk = (const float*)d_in[3];
    const float* bk = (const float*)d_in[4];
    const float* Wv = (const float*)d_in[5];
    const float* bv = (const float*)d_in[6];
    const float* Wo = (const float*)d_in[7];
    const float* bo = (const float*)d_in[8];

    size_t pelem = (size_t)BATCH * PBE;            // 8,912,896 per tensor
    ushort* qp  = (ushort*)d_ws;
    ushort* kp  = qp + pelem;
    ushort* vp  = kp + pelem;
    ushort* ctx = vp + pelem;                      // bf16 [16384][448]
    ushort* wt  = ctx + (size_t)BATCH * SEQ * KP;  // 4 x [448][448] bf16
    ushort* hsb = (ushort*)d_out;                  // bf16 hs, dead before final GEMM writes

    // zero q/k/v pads + ctx pad cols (contiguous region)
    hipMemsetAsync(d_ws, 0, (3 * pelem + (size_t)BATCH * SEQ * KP) * sizeof(ushort), stream);

    convert_hs<<<BATCH * SEQ * 56 / 256, 256, 0, stream>>>(hs, hsb);
    convert_w<<<dim3(KP * 56 / 256, 4), 256, 0, stream>>>(Wq, Wk, Wv, Wo, wt);

    dim3 gg(BATCH * SEQ / 128, KP / 64);           // 128 x 7
    gemm_mfma<0><<<gg, 256, 0, stream>>>(hsb, wt + 0 * (size_t)WTS, bq, qp);  // Q (pre-scaled)
    gemm_mfma<3><<<gg, 256, 0, stream>>>(hsb, wt + 1 * (size_t)WTS, bk, kp);  // K
    gemm_mfma<1><<<gg, 256, 0, stream>>>(hsb, wt + 2 * (size_t)WTS, bv, vp);  // V (transposed)

    attn_mfma<<<SEQ / 32 * NH * BATCH, 128, 0, stream>>>(qp, kp, vp, ctx);

    gemm_mfma<2><<<gg, 256, 0, stream>>>(ctx, wt + 3 * (size_t)WTS, bo, d_out);
}

// Round 9
// 343.754 us; speedup vs baseline: 13.0202x; 1.0932x over previous
//
#include <hip/hip_runtime.h>
#include <math.h>

#define BATCH 16
#define SEQ   1024
#define HID   441
#define NH    9
#define KP    448                 // padded hidden (K and N dim of GEMMs)
#define PB    544                 // sum of padded head dims
#define PBE   (SEQ * PB)          // padded elems per batch
#define WTS   (KP * KP)           // one transposed weight matrix

typedef __attribute__((ext_vector_type(8))) short bf16x8;
typedef __attribute__((ext_vector_type(4))) float f32x4;

__constant__ int c_bounds[NH + 1] = {0, 7, 21, 49, 105, 161, 217, 273, 357, 441};
__constant__ int c_dpad[NH] = {32, 32, 32, 64, 64, 64, 64, 96, 96};
__constant__ int c_cum[NH]  = {0, 32, 64, 96, 160, 224, 288, 352, 448};

__device__ __forceinline__ ushort f2bf(float x) {
    union { float f; unsigned u; } v; v.f = x;
    unsigned r = v.u + 0x7FFF + ((v.u >> 16) & 1);   // RNE
    return (ushort)(r >> 16);
}

__device__ __forceinline__ void gld_lds16(const ushort* g, ushort* l) {
    __builtin_amdgcn_global_load_lds(
        (const __attribute__((address_space(1))) unsigned int*)g,
        (__attribute__((address_space(3))) unsigned int*)l, 16, 0, 0);
}

// ---------------------------------------------------------------------------
// hs fp32 [16384][441] -> bf16 [16384][448] (pad cols zeroed)
// ---------------------------------------------------------------------------
__global__ __launch_bounds__(256)
void convert_hs(const float* __restrict__ hs, ushort* __restrict__ out)
{
    int t = blockIdx.x * 256 + threadIdx.x;   // 16384*56 threads
    int r = t / 56, cc = t % 56;
    const float* src = hs + (size_t)r * HID + cc * 8;
    union { ushort u[8]; bf16x8 v; } pk;
#pragma unroll
    for (int j = 0; j < 8; ++j) {
        int c = cc * 8 + j;
        pk.u[j] = (c < HID) ? f2bf(src[j]) : (ushort)0;
    }
    *(bf16x8*)(out + (size_t)r * KP + cc * 8) = pk.v;
}

// ---------------------------------------------------------------------------
// W fp32 [441][441] -> W^T bf16 [448][448] (pads zero). blockIdx.y = matrix.
// ---------------------------------------------------------------------------
__global__ __launch_bounds__(256)
void convert_w(const float* __restrict__ W0, const float* __restrict__ W1,
               const float* __restrict__ W2, const float* __restrict__ W3,
               ushort* __restrict__ wt)
{
    const float* W = (blockIdx.y == 0) ? W0 : (blockIdx.y == 1) ? W1
                   : (blockIdx.y == 2) ? W2 : W3;
    ushort* out = wt + (size_t)blockIdx.y * WTS;
    int t = blockIdx.x * 256 + threadIdx.x;   // 448*56 threads
    int n = t / 56, kc = t % 56;
    union { ushort u[8]; bf16x8 v; } pk;
#pragma unroll
    for (int j = 0; j < 8; ++j) {
        int k = kc * 8 + j;
        pk.u[j] = (k < HID && n < HID) ? f2bf(W[(size_t)k * HID + n]) : (ushort)0;
    }
    *(bf16x8*)(out + (size_t)n * KP + kc * 8) = pk.v;
}

// ---------------------------------------------------------------------------
// bf16 MFMA GEMM: C[16384, 448] = A[16384, 448] @ Bt[448, 448]^T + bias
// Tile 128x64, BK=32, 4 waves (2x2), global_load_lds staging, 1 barrier/step.
// MODE 0: Q — bf16 scatter -> padded [b][h][s][dp], PRE-SCALED by log2e/sqrt(d)
// MODE 3: K — bf16 scatter -> padded [b][h][s][dp], unscaled
// MODE 1: V — bf16 scatter -> transposed [b][h][dv][s]
// MODE 2: O — fp32 row-major [16384][441] + bias
// ---------------------------------------------------------------------------
template<int MODE>
__global__ __launch_bounds__(256)
void gemm_mfma(const ushort* __restrict__ A, const ushort* __restrict__ Bt,
               const float* __restrict__ bias, void* __restrict__ Cout)
{
    __shared__ ushort As[2][128 * 32];   // per buffer: 128 rows x 32 K = 4096 ushorts
    __shared__ ushort Bs[2][64 * 32];

    int tid = threadIdx.x;
    int wid = tid >> 6, lane = tid & 63;
    int wm = wid >> 1, wn = wid & 1;
    int lr = lane & 15, lg = lane >> 4;
    int m0 = blockIdx.x * 128, n0 = blockIdx.y * 64;

    const ushort* a_src = A + (size_t)(m0 + (tid >> 2)) * KP + (tid & 3) * 8;
    const ushort* b_src = Bt + (size_t)(n0 + (tid >> 2)) * KP + (tid & 3) * 8;

    f32x4 acc[4][2];
#pragma unroll
    for (int i = 0; i < 4; ++i)
#pragma unroll
        for (int j = 0; j < 2; ++j) acc[i][j] = (f32x4){0.f, 0.f, 0.f, 0.f};

    auto stage = [&](int buf, int k0) {
        gld_lds16(a_src + k0,            &As[buf][tid * 8]);
        gld_lds16(a_src + 64 * KP + k0,  &As[buf][2048 + tid * 8]);
        gld_lds16(b_src + k0,            &Bs[buf][tid * 8]);
    };

    stage(0, 0);
#pragma unroll 2
    for (int t = 0; t < 14; ++t) {
        int buf = t & 1;
        __syncthreads();                       // drains vmcnt+lgkm: buf staged, prev reads done
        if (t < 13) stage(buf ^ 1, (t + 1) * 32);

        bf16x8 af[4], bf[2];
#pragma unroll
        for (int mr = 0; mr < 4; ++mr)
            af[mr] = *(const bf16x8*)&As[buf][(wm * 64 + mr * 16 + lr) * 32 + lg * 8];
#pragma unroll
        for (int nt = 0; nt < 2; ++nt)
            bf[nt] = *(const bf16x8*)&Bs[buf][(wn * 32 + nt * 16 + lr) * 32 + lg * 8];
#pragma unroll
        for (int mr = 0; mr < 4; ++mr)
#pragma unroll
            for (int nt = 0; nt < 2; ++nt)
                acc[mr][nt] = __builtin_amdgcn_mfma_f32_16x16x32_bf16(af[mr], bf[nt], acc[mr][nt], 0, 0, 0);
    }

    // ---- epilogue ----
    int bb = m0 >> 10;
    int srow = (m0 & 1023) + wm * 64;

#pragma unroll
    for (int nt = 0; nt < 2; ++nt) {
        int gn = n0 + wn * 32 + nt * 16 + lr;
        bool ok = gn < HID;
        int gcl = ok ? gn : 0;
        float bval = ok ? bias[gcl] : 0.f;
        int hh = 0;
        while (gcl >= c_bounds[hh + 1]) ++hh;
        int off = gcl - c_bounds[hh];
        int dph = c_dpad[hh];
        size_t hbase = (size_t)bb * PBE + ((size_t)c_cum[hh] << 10);
        // Q pre-scale: fold log2e / sqrt(d) into Q so attention needs no score mul
        float cs = (MODE == 0)
                 ? rsqrtf((float)(c_bounds[hh + 1] - c_bounds[hh])) * 1.44269504f
                 : 1.0f;

#pragma unroll
        for (int mr = 0; mr < 4; ++mr)
#pragma unroll
            for (int r = 0; r < 4; ++r) {
                if (!ok) continue;
                int s = srow + mr * 16 + lg * 4 + r;
                float val = (acc[mr][nt][r] + bval) * cs;
                if (MODE == 0 || MODE == 3) {
                    ((ushort*)Cout)[hbase + (size_t)s * dph + off] = f2bf(val);
                } else if (MODE == 1) {
                    ((ushort*)Cout)[hbase + ((size_t)off << 10) + s] = f2bf(val);
                } else {
                    ((float*)Cout)[(size_t)(m0 + wm * 64 + mr * 16 + lg * 4 + r) * HID + gn] = val;
                }
            }
    }
}

// ---------------------------------------------------------------------------
// MFMA flash attention. 2-wave WGs, barrier-free, waves independent.
// DEEP-ILP variant: ALL K-fragments and V-fragments of a key tile are loaded
// into named register arrays up front (16-24 loads in flight per wave; V loads
// overlap QK^T+softmax). __launch_bounds__(128,2) -> 256-VGPR budget.
// KVB=64 for DP 32/64; KVB=32 for DP 96 (keeps frag arrays <=128 VGPR).
// Q pre-scaled (exp2 domain); K[s][DP] padded; V TRANSPOSED [dv][1024].
// ---------------------------------------------------------------------------
template<int DP, int KVB>
__device__ __forceinline__
void attn_body(const ushort* __restrict__ qp, const ushort* __restrict__ kp,
               const ushort* __restrict__ vp, ushort* __restrict__ ctx,
               ushort* __restrict__ Ps, int h, int b, int q0)
{
    constexpr int NDT = DP / 16;         // output col tiles (2/4/6)
    constexpr int NXC = DP / 32;         // K-dim chunks for QK (1/2/3)
    constexpr int NCT = KVB / 16;        // key sub-tiles per tile (4 or 2)
    constexpr int NKS = KVB / 32;        // PV K-chunks per tile (2 or 1)
    constexpr int M   = KVB / 8 - 1;     // Ps swizzle mask (7 or 3)

    int lane = threadIdx.x & 63;
    int lr = lane & 15, lg = lane >> 4;

    int s0 = c_bounds[h];
    int d  = c_bounds[h + 1] - s0;

    size_t base = (size_t)b * PBE + ((size_t)c_cum[h] << 10);
    const ushort* Q   = qp + base;
    const ushort* Kb  = kp + base;
    const ushort* Vtb = vp + base;

    int swz = (lr & M) << 3;

    bf16x8 aq[NXC];
    {
        int qrow = q0 + lr;
        const ushort* qr = Q + (size_t)qrow * DP + lg * 8;
#pragma unroll
        for (int xc = 0; xc < NXC; ++xc)
            aq[xc] = *(const bf16x8*)(qr + xc * 32);
    }

    f32x4 o[NDT];
#pragma unroll
    for (int i = 0; i < NDT; ++i) o[i] = (f32x4){0.f, 0.f, 0.f, 0.f};
    float mrow[4] = {-1e30f, -1e30f, -1e30f, -1e30f};
    float lrow[4] = {0.f, 0.f, 0.f, 0.f};

    for (int kt = 0; kt < SEQ; kt += KVB) {
        // ---- issue ALL K and V fragment loads for this tile ----
        bf16x8 kf[NCT][NXC];
#pragma unroll
        for (int ct = 0; ct < NCT; ++ct) {
            const ushort* kr = Kb + (size_t)(kt + ct * 16 + lr) * DP + lg * 8;
#pragma unroll
            for (int xc = 0; xc < NXC; ++xc)
                kf[ct][xc] = *(const bf16x8*)(kr + xc * 32);
        }
        bf16x8 vf[NDT][NKS];
#pragma unroll
        for (int dt = 0; dt < NDT; ++dt) {
            const ushort* vr = Vtb + ((size_t)(dt * 16 + lr) << 10) + kt + lg * 8;
#pragma unroll
            for (int ks = 0; ks < NKS; ++ks)
                vf[dt][ks] = *(const bf16x8*)(vr + ks * 32);
        }

        // ---- S = Q K^T (already exp2-scaled via Q) ----
        f32x4 sc[NCT];
        __builtin_amdgcn_s_setprio(1);
#pragma unroll
        for (int ct = 0; ct < NCT; ++ct) {
            f32x4 s = {0.f, 0.f, 0.f, 0.f};
#pragma unroll
            for (int xc = 0; xc < NXC; ++xc)
                s = __builtin_amdgcn_mfma_f32_16x16x32_bf16(aq[xc], kf[ct][xc], s, 0, 0, 0);
            sc[ct] = s;
        }
        __builtin_amdgcn_s_setprio(0);

        // ---- online softmax ----
        float mnew[4], fr[4];
#pragma unroll
        for (int r = 0; r < 4; ++r) {
            float mx = sc[0][r];
#pragma unroll
            for (int ct = 1; ct < NCT; ++ct) mx = fmaxf(mx, sc[ct][r]);
#pragma unroll
            for (int off = 1; off < 16; off <<= 1)
                mx = fmaxf(mx, __shfl_xor(mx, off));
            mnew[r] = fmaxf(mrow[r], mx);
            fr[r] = exp2f(mrow[r] - mnew[r]);
            mrow[r] = mnew[r];
        }
#pragma unroll
        for (int r = 0; r < 4; ++r) {
            int row = lg * 4 + r;
            int wsz = (row & M) << 3;
            float sum = 0.f;
#pragma unroll
            for (int ct = 0; ct < NCT; ++ct) {
                float p = exp2f(sc[ct][r] - mnew[r]);
                sum += p;
                // round-half-up bf16 (2 VALU ops; no systematic bias)
                Ps[row * KVB + ((lr + ct * 16) ^ wsz)] =
                    (ushort)((__builtin_bit_cast(unsigned, p) + 0x8000u) >> 16);
            }
#pragma unroll
            for (int off = 1; off < 16; off <<= 1)
                sum += __shfl_xor(sum, off);
            lrow[r] = lrow[r] * fr[r] + sum;
        }

        // ---- O = fr*O + P V ----
        bf16x8 ap[NKS];
#pragma unroll
        for (int ks = 0; ks < NKS; ++ks)
            ap[ks] = *(const bf16x8*)&Ps[lr * KVB + ((ks * 32 + lg * 8) ^ swz)];

        __builtin_amdgcn_s_setprio(1);
#pragma unroll
        for (int dt = 0; dt < NDT; ++dt) {
#pragma unroll
            for (int r = 0; r < 4; ++r) o[dt][r] *= fr[r];
#pragma unroll
            for (int ks = 0; ks < NKS; ++ks)
                o[dt] = __builtin_amdgcn_mfma_f32_16x16x32_bf16(ap[ks], vf[dt][ks], o[dt], 0, 0, 0);
        }
        __builtin_amdgcn_s_setprio(0);
    }

    // ---- write ctx (bf16, padded [s][448] layout) ----
#pragma unroll
    for (int r = 0; r < 4; ++r) {
        float inv = 1.0f / lrow[r];
        int q = q0 + lg * 4 + r;
        ushort* dst = ctx + ((size_t)(b << 10) + q) * KP + s0;
#pragma unroll
        for (int dt = 0; dt < NDT; ++dt) {
            int dv = lr + 16 * dt;
            if (dv < d) dst[dv] = f2bf(o[dt][r] * inv);
        }
    }
}

__global__ __launch_bounds__(128, 2)
void attn_mfma(const ushort* __restrict__ qp, const ushort* __restrict__ kp,
               const ushort* __restrict__ vp, ushort* __restrict__ ctx)
{
    __shared__ ushort Ps[2][16 * 64];        // 4 KB / 2-wave workgroup
    int wave = threadIdx.x >> 6;
    // XCD-group swizzle: all 32 WGs of one (b,h) land on one XCD.
    // 4608 WGs = 8 xcd x 576 slots; 144 groups = 8 x 18 — bijective.
    int i = blockIdx.x;
    int xcd = i & 7, slot = i >> 3;          // slot 0..575
    int group = xcd + 8 * (slot >> 5);       // 0..143
    int sub = slot & 31;                     // 32-row tile within group
    int b = group / NH, h = group % NH;
    int q0 = sub * 32 + wave * 16;
    if (h < 3)      attn_body<32, 64>(qp, kp, vp, ctx, Ps[wave], h, b, q0);
    else if (h < 7) attn_body<64, 64>(qp, kp, vp, ctx, Ps[wave], h, b, q0);
    else            attn_body<96, 32>(qp, kp, vp, ctx, Ps[wave], h, b, q0);
}

// ---------------------------------------------------------------------------
extern "C" void kernel_launch(void* const* d_in, const int* in_sizes, int n_in,
                              void* d_out, int out_size, void* d_ws, size_t ws_size,
                              hipStream_t stream)
{
    const float* hs = (const float*)d_in[0];
    const float* Wq = (const float*)d_in[1];
    const float* bq = (const float*)d_in[2];
    const float* Wk = (const float*)d_in[3];
    const float* bk = (const float*)d_in[4];
    const float* Wv = (const float*)d_in[5];
    const float* bv = (const float*)d_in[6];
    const float* Wo = (const float*)d_in[7];
    const float* bo = (const float*)d_in[8];

    size_t pelem = (size_t)BATCH * PBE;            // 8,912,896 per tensor
    ushort* qp  = (ushort*)d_ws;
    ushort* kp  = qp + pelem;
    ushort* vp  = kp + pelem;
    ushort* ctx = vp + pelem;                      // bf16 [16384][448]
    ushort* wt  = ctx + (size_t)BATCH * SEQ * KP;  // 4 x [448][448] bf16
    ushort* hsb = (ushort*)d_out;                  // bf16 hs, dead before final GEMM writes

    // zero q/k/v pads + ctx pad cols (contiguous region)
    hipMemsetAsync(d_ws, 0, (3 * pelem + (size_t)BATCH * SEQ * KP) * sizeof(ushort), stream);

    convert_hs<<<BATCH * SEQ * 56 / 256, 256, 0, stream>>>(hs, hsb);
    convert_w<<<dim3(KP * 56 / 256, 4), 256, 0, stream>>>(Wq, Wk, Wv, Wo, wt);

    dim3 gg(BATCH * SEQ / 128, KP / 64);           // 128 x 7
    gemm_mfma<0><<<gg, 256, 0, stream>>>(hsb, wt + 0 * (size_t)WTS, bq, qp);  // Q (pre-scaled)
    gemm_mfma<3><<<gg, 256, 0, stream>>>(hsb, wt + 1 * (size_t)WTS, bk, kp);  // K
    gemm_mfma<1><<<gg, 256, 0, stream>>>(hsb, wt + 2 * (size_t)WTS, bv, vp);  // V (transposed)

    attn_mfma<<<SEQ / 32 * NH * BATCH, 128, 0, stream>>>(qp, kp, vp, ctx);

    gemm_mfma<2><<<gg, 256, 0, stream>>>(ctx, wt + 3 * (size_t)WTS, bo, d_out);
}